// Round 10
// baseline (547.627 us; speedup 1.0000x reference)
//
#include <hip/hip_runtime.h>
#include <math.h>
#include <stdint.h>

#define NND  100000   // nodes
#define NED  1600000  // edges (without self loops)
#define FIN  512
#define HID  128
#define ENC  64
#define NCLS 10
#define DOM  40

#define SCAN_BS 256
#define NBS ((NND + SCAN_BS - 1) / SCAN_BS)   // 391

typedef __attribute__((ext_vector_type(8))) short short8v;
typedef __attribute__((ext_vector_type(8))) unsigned short ushort8v;
typedef __attribute__((ext_vector_type(4))) float f32x4;
typedef __attribute__((ext_vector_type(4))) unsigned int uint4v;

// ---------------- helpers ----------------

__device__ inline void split8(const float4 a, const float4 b,
                              short8v& hi, short8v& lo) {
  float f[8] = {a.x, a.y, a.z, a.w, b.x, b.y, b.z, b.w};
  uint4v H, L;
#pragma unroll
  for (int i = 0; i < 4; ++i) {
    unsigned int u0 = __float_as_uint(f[2 * i]);
    unsigned int u1 = __float_as_uint(f[2 * i + 1]);
    H[i] = (u0 >> 16) | (u1 & 0xffff0000u);
    float l0 = f[2 * i]     - __uint_as_float(u0 & 0xffff0000u);
    float l1 = f[2 * i + 1] - __uint_as_float(u1 & 0xffff0000u);
    L[i] = (__float_as_uint(l0) >> 16) | (__float_as_uint(l1) & 0xffff0000u);
  }
  hi = __builtin_bit_cast(short8v, H);
  lo = __builtin_bit_cast(short8v, L);
}

__device__ inline ushort f2bf_rne(float x) {
  unsigned int u = __float_as_uint(x);
  unsigned int r = u + 0x7fffu + ((u >> 16) & 1u);
  return (ushort)(r >> 16);
}

__device__ inline float bf2f(unsigned short v) {
  return __uint_as_float((unsigned int)v << 16);
}

__device__ inline void gload_lds16(const float* gp, float* lp) {
  __builtin_amdgcn_global_load_lds(
      (const __attribute__((address_space(1))) void*)gp,
      (__attribute__((address_space(3))) void*)lp, 16, 0, 0);
}

// ---------------- prep: zero packed + convert W1/W2 to split-bf16 ------------
// one launch; grid = max(NND, FIN*HID + HID*ENC) / 256

__global__ void k_prep(const float* __restrict__ W1, ushort* __restrict__ b1hi,
                       ushort* __restrict__ b1lo, const float* __restrict__ W2,
                       ushort* __restrict__ b2hi, ushort* __restrict__ b2lo,
                       unsigned long long* __restrict__ packed) {
  int id = blockIdx.x * 256 + threadIdx.x;
  if (id < NND) packed[id] = 0ull;
  const float* B; ushort *bhi, *blo; int NC;
  if (id < FIN * HID) { B = W1; bhi = b1hi; blo = b1lo; NC = HID; }
  else {
    id -= FIN * HID;
    if (id >= HID * ENC) return;
    B = W2; bhi = b2hi; blo = b2lo; NC = ENC;
  }
  int k = id / NC, c = id % NC;
  float x = B[id];
  unsigned int u = __float_as_uint(x);
  ushort h = (ushort)(u >> 16);
  float lo = x - __uint_as_float(u & 0xffff0000u);
  ushort l = (ushort)(__float_as_uint(lo) >> 16);
  size_t o = ((size_t)(k >> 3) * NC + c) * 8 + (k & 7);
  bhi[o] = h;
  blo[o] = l;
}

// ---------------- degree + rank: ONE packed 64-bit atomic per edge -----------
// packed[d]: bits [40,64) = count, bits [0,40) = sum(ppmi) in 2^-30 fixed pt.

__global__ void k_deg_rank(const int* __restrict__ dst, const float* __restrict__ ppmi,
                           unsigned long long* __restrict__ packed,
                           int* __restrict__ rank) {
  int e = blockIdx.x * blockDim.x + threadIdx.x;
  if (e >= NED) return;
  int d = dst[e];
  unsigned int fx = (unsigned int)(ppmi[e] * 1073741824.0f + 0.5f);
  unsigned long long v = (1ull << 40) | (unsigned long long)fx;
  unsigned long long old = atomicAdd(&packed[d], v);
  rank[e] = (int)(old >> 40);
}

// ---------------- dinv + scan_a fused (per-node pass) ------------------------

__global__ void k_dinv_scan(const unsigned long long* __restrict__ packed,
                            float* __restrict__ dinv_g, float* __restrict__ dinv_p,
                            int* __restrict__ psum) {
  __shared__ int s[SCAN_BS];
  int t = threadIdx.x, i = blockIdx.x * SCAN_BS + t;
  int cnt = 0;
  if (i < NND) {
    unsigned long long pk = packed[i];
    cnt = (int)(pk >> 40);
    float dp = (float)(pk & 0xFFFFFFFFFFull) * (1.0f / 1073741824.0f);
    dinv_g[i] = 1.0f / sqrtf((float)cnt + 1.0f);
    dinv_p[i] = 1.0f / sqrtf(dp + 1.0f);
  }
  s[t] = cnt;
  __syncthreads();
  for (int o = SCAN_BS / 2; o; o >>= 1) {
    if (t < o) s[t] += s[t + o];
    __syncthreads();
  }
  if (t == 0) psum[blockIdx.x] = s[0];
}

__global__ void k_scan_b(int* __restrict__ psum) {
  __shared__ int s[512];
  int t = threadIdx.x;
  int v = (t < NBS) ? psum[t] : 0;
  s[t] = v;
  __syncthreads();
  for (int o = 1; o < 512; o <<= 1) {
    int add = (t >= o) ? s[t - o] : 0;
    __syncthreads();
    s[t] += add;
    __syncthreads();
  }
  if (t < NBS) psum[t] = s[t] - v;   // exclusive
}

__global__ void k_scan_c(const unsigned long long* __restrict__ packed,
                         const int* __restrict__ psum, int* __restrict__ row_ptr) {
  __shared__ int s[SCAN_BS];
  int t = threadIdx.x, i = blockIdx.x * SCAN_BS + t;
  int v = (i < NND) ? (int)(packed[i] >> 40) : 0;
  s[t] = v;
  __syncthreads();
  for (int o = 1; o < SCAN_BS; o <<= 1) {
    int add = (t >= o) ? s[t - o] : 0;
    __syncthreads();
    s[t] += add;
    __syncthreads();
  }
  if (i < NND) row_ptr[i] = psum[blockIdx.x] + s[t] - v;
  if (i == NND - 1) row_ptr[NND] = psum[blockIdx.x] + s[t];
}

// ---------------- CSR scatter: 8B record {src, gn_bf16|pn_bf16<<16} ----------

__global__ void k_scatter(const int* __restrict__ src, const int* __restrict__ dst,
                          const float* __restrict__ ppmi,
                          const int* __restrict__ row_ptr, const int* __restrict__ rank,
                          const float* __restrict__ dinv_g, const float* __restrict__ dinv_p,
                          int2* __restrict__ csr) {
  int e = blockIdx.x * blockDim.x + threadIdx.x;
  if (e >= NED) return;
  int s = src[e], d = dst[e];
  int pos = row_ptr[d] + rank[e];
  ushort gn = f2bf_rne(dinv_g[s] * dinv_g[d]);
  ushort pn = f2bf_rne(dinv_p[s] * ppmi[e] * dinv_p[d]);
  int2 rec;
  rec.x = s;
  rec.y = (int)gn | ((int)pn << 16);
  csr[pos] = rec;
}

// ---------------- GEMM1: h_linb(bf16) = x @ W1, LDS-staged split-bf16 MFMA ---
// 128x128 tile, BK=32, 4 waves (2x2). A fp32 -> LDS via global_load_lds w=16,
// double-buffered; 16B-chunk XOR swizzle (chunk ^= row&7) on global source and
// ds_read (both-sides involution, LDS dest linear).

__global__ __launch_bounds__(256, 4) void gemm1_lds(
    const float* __restrict__ A, const ushort* __restrict__ Bhi,
    const ushort* __restrict__ Blo, ushort* __restrict__ C) {
  __shared__ float At[2][128 * 32];
  const int tid = threadIdx.x;
  const int lane = tid & 63;
  const int w = tid >> 6;
  const int wr = w >> 1, wc = w & 1;
  const int g = lane >> 4;
  const int l16 = lane & 15;
  const int row_base = blockIdx.x * 128;

  size_t srow[4]; int scol[4];
  {
    int e = w * 256 + lane * 4;
#pragma unroll
    for (int i = 0; i < 4; ++i) {
      int ee = e + i * 1024;
      int r = ee >> 5;
      int chunk_lds = (ee >> 2) & 7;
      int chunk_g = chunk_lds ^ (r & 7);
      int rr = row_base + r; if (rr >= NND) rr = NND - 1;
      srow[i] = (size_t)rr * FIN;
      scol[i] = chunk_g * 4;
    }
  }

  int coln[4];
#pragma unroll
  for (int n = 0; n < 4; ++n) coln[n] = wc * 64 + n * 16 + l16;
  int arow_l[4];
#pragma unroll
  for (int m = 0; m < 4; ++m) arow_l[m] = wr * 64 + m * 16 + l16;

  f32x4 acc[4][4] = {};

#pragma unroll
  for (int i = 0; i < 4; ++i)
    gload_lds16(A + srow[i] + 0 + scol[i], &At[0][w * 256 + i * 1024]);
  __syncthreads();

  for (int t = 0; t < FIN / 32; ++t) {
    const int cur = t & 1;
    if (t + 1 < FIN / 32) {
      const int k0n = (t + 1) * 32;
#pragma unroll
      for (int i = 0; i < 4; ++i)
        gload_lds16(A + srow[i] + k0n + scol[i], &At[cur ^ 1][w * 256 + i * 1024]);
    }

    short8v ah[4], al[4];
#pragma unroll
    for (int m = 0; m < 4; ++m) {
      int r = arow_l[m];
      int c0 = (((g * 2)     ^ (r & 7)) << 2);
      int c1 = (((g * 2 + 1) ^ (r & 7)) << 2);
      float4 a0 = *(const float4*)&At[cur][r * 32 + c0];
      float4 a1 = *(const float4*)&At[cur][r * 32 + c1];
      split8(a0, a1, ah[m], al[m]);
    }

    short8v bh[4], bl[4];
    const int kc = t * 4 + g;
#pragma unroll
    for (int n = 0; n < 4; ++n) {
      size_t off = ((size_t)kc * HID + coln[n]) * 8;
      bh[n] = *(const short8v*)(Bhi + off);
      bl[n] = *(const short8v*)(Blo + off);
    }

#pragma unroll
    for (int m = 0; m < 4; ++m)
#pragma unroll
      for (int n = 0; n < 4; ++n) {
        acc[m][n] = __builtin_amdgcn_mfma_f32_16x16x32_bf16(ah[m], bh[n], acc[m][n], 0, 0, 0);
        acc[m][n] = __builtin_amdgcn_mfma_f32_16x16x32_bf16(al[m], bh[n], acc[m][n], 0, 0, 0);
        acc[m][n] = __builtin_amdgcn_mfma_f32_16x16x32_bf16(ah[m], bl[n], acc[m][n], 0, 0, 0);
      }

    __syncthreads();
  }

  // C/D layout: col = lane&15, row = (lane>>4)*4 + reg; wave offset wr*64 included
#pragma unroll
  for (int m = 0; m < 4; ++m)
#pragma unroll
    for (int i = 0; i < 4; ++i) {
      int r = row_base + wr * 64 + m * 16 + g * 4 + i;
      if (r < NND) {
#pragma unroll
        for (int n = 0; n < 4; ++n)
          C[(size_t)r * HID + coln[n]] = f2bf_rne(acc[m][n][i]);
      }
    }
}

// ---------------- GEMM2: h2b(bf16) = [hg;hp] @ W2, register-A bf16 -----------

template<int WR>
__global__ __launch_bounds__(256, 6) void gemm2_split(
    const ushort* __restrict__ As, const ushort* __restrict__ Bhi,
    const ushort* __restrict__ Blo, ushort* __restrict__ C,
    int M, int K, int Nc) {
  const int lane = threadIdx.x & 63;
  const int w = threadIdx.x >> 6;
  const int g = lane >> 4;
  const int l16 = lane & 15;
  const int row_base = blockIdx.x * (WR * 64) + w * 64;

  size_t arow[4];
#pragma unroll
  for (int m = 0; m < 4; ++m) {
    int r = row_base + m * 16 + l16;
    if (r >= M) r = M - 1;
    arow[m] = (size_t)r * K;
  }
  int coln[4];
#pragma unroll
  for (int n = 0; n < 4; ++n) coln[n] = n * 16 + l16;

  f32x4 acc[4][4] = {};

  for (int k0 = 0; k0 < K; k0 += 32) {
    short8v ah[4];
#pragma unroll
    for (int m = 0; m < 4; ++m)
      ah[m] = *(const short8v*)(As + arow[m] + k0 + g * 8);
    short8v bh[4], bl[4];
    const int kc = (k0 >> 3) + g;
#pragma unroll
    for (int n = 0; n < 4; ++n) {
      size_t off = ((size_t)kc * Nc + coln[n]) * 8;
      bh[n] = *(const short8v*)(Bhi + off);
      bl[n] = *(const short8v*)(Blo + off);
    }
#pragma unroll
    for (int m = 0; m < 4; ++m)
#pragma unroll
      for (int n = 0; n < 4; ++n) {
        acc[m][n] = __builtin_amdgcn_mfma_f32_16x16x32_bf16(ah[m], bh[n], acc[m][n], 0, 0, 0);
        acc[m][n] = __builtin_amdgcn_mfma_f32_16x16x32_bf16(ah[m], bl[n], acc[m][n], 0, 0, 0);
      }
  }

#pragma unroll
  for (int m = 0; m < 4; ++m)
#pragma unroll
    for (int i = 0; i < 4; ++i) {
      int r = row_base + m * 16 + g * 4 + i;
      if (r < M) {
#pragma unroll
        for (int n = 0; n < 4; ++n) {
          int c = coln[n];
          size_t o = (r < NND) ? ((size_t)r * 128 + c)
                               : ((size_t)(r - NND) * 128 + 64 + c);
          C[o] = f2bf_rne(acc[m][n][i]);
        }
      }
    }
}

// ---------------- layer-1 aggregation: bf16 gathers, 4 edges in flight -------

__global__ __launch_bounds__(256) void k_agg1(
    const ushort* __restrict__ hlinb, const int* __restrict__ row_ptr,
    const int2* __restrict__ csr,
    const float* __restrict__ dinv_g, const float* __restrict__ dinv_p,
    const float* __restrict__ b1, ushort* __restrict__ hhs) {
  int wid = (blockIdx.x * blockDim.x + threadIdx.x) >> 6;
  int lane = threadIdx.x & 63;
  if (wid >= NND) return;
  const int gp = lane >> 4;
  const int t  = lane & 15;
  float sg = dinv_g[wid]; sg *= sg;
  float sp = dinv_p[wid]; sp *= sp;

  float ag[8] = {}, ap[8] = {};
  if (gp == 0) {
    ushort8v v = *(const ushort8v*)(hlinb + (size_t)wid * HID + 8 * t);
#pragma unroll
    for (int i = 0; i < 8; ++i) {
      float f = bf2f(v[i]);
      ag[i] = f * sg; ap[i] = f * sp;
    }
  }
  int e0 = row_ptr[wid], e1 = row_ptr[wid + 1];
  int k = e0 + gp;
  if (k < e1) {
    int2 rec = csr[k];
    while (true) {
      int kn = k + 4;
      int2 nrec = csr[kn < e1 ? kn : k];      // clamped prefetch
      float wg = bf2f((ushort)(rec.y & 0xffff));
      float wp = bf2f((ushort)((unsigned)rec.y >> 16));
      ushort8v u = *(const ushort8v*)(hlinb + (size_t)rec.x * HID + 8 * t);
#pragma unroll
      for (int i = 0; i < 8; ++i) {
        float f = bf2f(u[i]);
        ag[i] = fmaf(f, wg, ag[i]);
        ap[i] = fmaf(f, wp, ap[i]);
      }
      if (kn >= e1) break;
      k = kn; rec = nrec;
    }
  }
#pragma unroll
  for (int i = 0; i < 8; ++i) {
    ag[i] += __shfl_xor(ag[i], 32); ap[i] += __shfl_xor(ap[i], 32);
    ag[i] += __shfl_xor(ag[i], 16); ap[i] += __shfl_xor(ap[i], 16);
  }

  float bb[8];
  *(float4*)&bb[0] = *(const float4*)(b1 + 8 * t);
  *(float4*)&bb[4] = *(const float4*)(b1 + 8 * t + 4);
  if (gp == 0 || gp == 2) {
    ushort8v outv;
#pragma unroll
    for (int i = 0; i < 8; ++i) {
      float v = (gp == 0) ? fmaxf(ag[i] + bb[i], 0.f) : fmaxf(ap[i] + bb[i], 0.f);
      outv[i] = f2bf_rne(v);
    }
    size_t row = (gp == 0) ? (size_t)wid : (size_t)(NND + wid);
    *(ushort8v*)(hhs + row * HID + 8 * t) = outv;
  }
}

// ---------------- layer-2 aggregation + attention -> emb ---------------------

__global__ __launch_bounds__(256) void k_agg2(
    const ushort* __restrict__ h2b, const int* __restrict__ row_ptr,
    const int2* __restrict__ csr,
    const float* __restrict__ dinv_g, const float* __restrict__ dinv_p,
    const float* __restrict__ b2, const float* __restrict__ att_w,
    const float* __restrict__ att_b, float* __restrict__ out_emb) {
  int wid = (blockIdx.x * blockDim.x + threadIdx.x) >> 6;
  int lane = threadIdx.x & 63;
  if (wid >= NND) return;
  const int gp = lane >> 4;
  const int t  = lane & 15;
  const int br = t >> 3;            // 0 = g branch, 1 = p branch
  const int f0 = (t & 7) * 8;       // feature base within branch
  float sg = dinv_g[wid]; sg *= sg;
  float sp = dinv_p[wid]; sp *= sp;
  const float sw = br ? sp : sg;

  float acc[8] = {};
  if (gp == 0) {
    ushort8v v = *(const ushort8v*)(h2b + (size_t)wid * 128 + 8 * t);
#pragma unroll
    for (int i = 0; i < 8; ++i) acc[i] = bf2f(v[i]) * sw;
  }
  int e0 = row_ptr[wid], e1 = row_ptr[wid + 1];
  int k = e0 + gp;
  if (k < e1) {
    int2 rec = csr[k];
    while (true) {
      int kn = k + 4;
      int2 nrec = csr[kn < e1 ? kn : k];
      float w = br ? bf2f((ushort)((unsigned)rec.y >> 16))
                   : bf2f((ushort)(rec.y & 0xffff));
      ushort8v u = *(const ushort8v*)(h2b + (size_t)rec.x * 128 + 8 * t);
#pragma unroll
      for (int i = 0; i < 8; ++i) acc[i] = fmaf(bf2f(u[i]), w, acc[i]);
      if (kn >= e1) break;
      k = kn; rec = nrec;
    }
  }
#pragma unroll
  for (int i = 0; i < 8; ++i) {
    acc[i] += __shfl_xor(acc[i], 32);
    acc[i] += __shfl_xor(acc[i], 16);
  }

  float bb[8];
  *(float4*)&bb[0] = *(const float4*)(b2 + f0);
  *(float4*)&bb[4] = *(const float4*)(b2 + f0 + 4);
  float v[8];
#pragma unroll
  for (int i = 0; i < 8; ++i) v[i] = acc[i] + bb[i];

  float aw[8];
  *(float4*)&aw[0] = *(const float4*)(att_w + f0);
  *(float4*)&aw[4] = *(const float4*)(att_w + f0 + 4);
  float part = 0.f;
#pragma unroll
  for (int i = 0; i < 8; ++i) part = fmaf(v[i], aw[i], part);
  part += __shfl_xor(part, 4);
  part += __shfl_xor(part, 2);
  part += __shfl_xor(part, 1);
  float other = __shfl_xor(part, 8);
  float ab = att_b[0];
  float lg = (br ? other : part) + ab;
  float lp = (br ? part : other) + ab;
  float mx = fmaxf(lg, lp);
  float eg = expf(lg - mx), ep2 = expf(lp - mx);
  float wsm = eg / (eg + ep2);          // weight of g branch

  float ov[8];
#pragma unroll
  for (int i = 0; i < 8; ++i) ov[i] = __shfl_xor(v[i], 8);
  if (gp == 0 && br == 0) {
    float4* dst = (float4*)(out_emb + (size_t)wid * 64 + f0);
    float4 o0, o1;
    o0.x = wsm * v[0] + (1.f - wsm) * ov[0];
    o0.y = wsm * v[1] + (1.f - wsm) * ov[1];
    o0.z = wsm * v[2] + (1.f - wsm) * ov[2];
    o0.w = wsm * v[3] + (1.f - wsm) * ov[3];
    o1.x = wsm * v[4] + (1.f - wsm) * ov[4];
    o1.y = wsm * v[5] + (1.f - wsm) * ov[5];
    o1.z = wsm * v[6] + (1.f - wsm) * ov[6];
    o1.w = wsm * v[7] + (1.f - wsm) * ov[7];
    dst[0] = o0;
    dst[1] = o1;
  }
}

// ---------------- class + domain heads --------------

__global__ __launch_bounds__(128) void k_head(
    const float* __restrict__ emb,
    const float* __restrict__ cls_w, const float* __restrict__ cls_b,
    const float* __restrict__ dw1, const float* __restrict__ db1,
    const float* __restrict__ dw2, const float* __restrict__ db2,
    float* __restrict__ out_cls, float* __restrict__ out_dom) {
  __shared__ float se[128 * 65];
  const int t = threadIdx.x;
  const int base = blockIdx.x * 128;
  for (int c = 0; c < 64; ++c) {
    int idx = c * 128 + t;
    int nl = idx >> 6, k = idx & 63;
    size_t g = (size_t)base * ENC + idx;
    float v = (g < (size_t)NND * ENC) ? emb[g] : 0.f;
    se[nl * 65 + k] = v;
  }
  __syncthreads();

  int node = base + t;
  float c[NCLS], hd[DOM];
#pragma unroll
  for (int j = 0; j < NCLS; ++j) c[j] = cls_b[j];
#pragma unroll
  for (int j = 0; j < DOM; ++j) hd[j] = db1[j];

  for (int k = 0; k < ENC; ++k) {
    float ev = se[t * 65 + k];
#pragma unroll
    for (int j = 0; j < NCLS; ++j) c[j] += ev * cls_w[k * NCLS + j];
#pragma unroll
    for (int j = 0; j < DOM; ++j) hd[j] += ev * dw1[k * DOM + j];
  }
  float d0 = db2[0], d1 = db2[1];
#pragma unroll
  for (int j = 0; j < DOM; ++j) {
    float hv = fmaxf(hd[j], 0.f);
    d0 += hv * dw2[j * 2];
    d1 += hv * dw2[j * 2 + 1];
  }
  if (node < NND) {
#pragma unroll
    for (int j = 0; j < NCLS; ++j) out_cls[(size_t)node * NCLS + j] = c[j];
    out_dom[(size_t)node * 2]     = d0;
    out_dom[(size_t)node * 2 + 1] = d1;
  }
}

// ---------------- host ----------------

extern "C" void kernel_launch(void* const* d_in, const int* in_sizes, int n_in,
                              void* d_out, int out_size, void* d_ws, size_t ws_size,
                              hipStream_t stream) {
  const float* x     = (const float*)d_in[0];
  const int*   ei    = (const int*)d_in[1];
  const float* ppmi  = (const float*)d_in[2];
  const float* W1    = (const float*)d_in[4];
  const float* b1    = (const float*)d_in[5];
  const float* W2    = (const float*)d_in[6];
  const float* b2    = (const float*)d_in[7];
  const float* att_w = (const float*)d_in[8];
  const float* att_b = (const float*)d_in[9];
  const float* cls_w = (const float*)d_in[10];
  const float* cls_b = (const float*)d_in[11];
  const float* dw1   = (const float*)d_in[12];
  const float* db1   = (const float*)d_in[13];
  const float* dw2   = (const float*)d_in[14];
  const float* db2   = (const float*)d_in[15];

  const int* src = ei;
  const int* dst = ei + NED;

  uintptr_t p = (uintptr_t)d_ws;
  auto alloc = [&](size_t bytes) -> void* {
    void* r = (void*)p;
    p += (bytes + 255) & ~(size_t)255;
    return r;
  };
  unsigned long long* packed = (unsigned long long*)alloc((size_t)NND * 8);
  int*    rank    = (int*)   alloc((size_t)NED * 4);
  int*    row_ptr = (int*)   alloc((size_t)(NND + 1) * 4);
  int*    psum    = (int*)   alloc((size_t)NBS * 4);
  float*  dinv_g  = (float*) alloc((size_t)NND * 4);
  float*  dinv_p  = (float*) alloc((size_t)NND * 4);
  int2*   csr     = (int2*)  alloc((size_t)NED * 8);
  ushort* b1hi    = (ushort*)alloc((size_t)FIN * HID * 2);
  ushort* b1lo    = (ushort*)alloc((size_t)FIN * HID * 2);
  ushort* b2hi    = (ushort*)alloc((size_t)HID * ENC * 2);
  ushort* b2lo    = (ushort*)alloc((size_t)HID * ENC * 2);
  ushort* h2b     = (ushort*)alloc((size_t)NND * HID * 2);        // bf16 h2 pair
  ushort* hhs     = (ushort*)alloc((size_t)2 * NND * HID * 2);    // bf16 hg|hp

  float* out_emb = (float*)d_out;
  float* out_cls = (float*)d_out + (size_t)NND * ENC;
  float* out_dom = (float*)d_out + (size_t)NND * (ENC + NCLS);

  // bf16 h_lin lives in the d_out emb region (NND*128*2B == NND*64*4B exactly);
  // dead before agg2 overwrites the region with emb.
  ushort* h_linb = (ushort*)d_out;

  // ---- prep (zero packed + weight conversion, one launch) ----
  k_prep<<<(NND + 255) / 256, 256, 0, stream>>>(W1, b1hi, b1lo, W2, b2hi, b2lo,
                                                packed);

  // ---- graph preprocessing ----
  k_deg_rank<<<NED / 256, 256, 0, stream>>>(dst, ppmi, packed, rank);
  k_dinv_scan<<<NBS, SCAN_BS, 0, stream>>>(packed, dinv_g, dinv_p, psum);
  k_scan_b<<<1, 512, 0, stream>>>(psum);
  k_scan_c<<<NBS, SCAN_BS, 0, stream>>>(packed, psum, row_ptr);
  k_scatter<<<NED / 256, 256, 0, stream>>>(src, dst, ppmi, row_ptr, rank,
                                           dinv_g, dinv_p, csr);

  // ---- encoder ----
  gemm1_lds<<<(NND + 127) / 128, 256, 0, stream>>>(x, b1hi, b1lo, h_linb);
  k_agg1<<<(NND * 64) / 256, 256, 0, stream>>>(h_linb, row_ptr, csr,
                                               dinv_g, dinv_p, b1, hhs);
  gemm2_split<4><<<(2 * NND + 255) / 256, 256, 0, stream>>>(
      hhs, b2hi, b2lo, h2b, 2 * NND, HID, ENC);
  k_agg2<<<(NND * 64) / 256, 256, 0, stream>>>(h2b, row_ptr, csr,
                                               dinv_g, dinv_p, b2, att_w, att_b, out_emb);

  // ---- heads ----
  k_head<<<(NND + 127) / 128, 128, 0, stream>>>(out_emb, cls_w, cls_b, dw1, db1,
                                                dw2, db2, out_cls, out_dom);
}

// Round 11
// 442.724 us; speedup vs baseline: 1.2369x; 1.2369x over previous
//
#include <hip/hip_runtime.h>
#include <math.h>
#include <stdint.h>

#define NND  100000   // nodes
#define NED  1600000  // edges (without self loops)
#define FIN  512
#define HID  128
#define ENC  64
#define NCLS 10
#define DOM  40

#define SCAN_BS 256
#define NBS ((NND + SCAN_BS - 1) / SCAN_BS)   // 391

typedef __attribute__((ext_vector_type(8))) short short8v;
typedef __attribute__((ext_vector_type(8))) unsigned short ushort8v;
typedef __attribute__((ext_vector_type(4))) float f32x4;
typedef __attribute__((ext_vector_type(4))) unsigned int uint4v;

// ---------------- helpers ----------------

__device__ inline void split8(const float4 a, const float4 b,
                              short8v& hi, short8v& lo) {
  float f[8] = {a.x, a.y, a.z, a.w, b.x, b.y, b.z, b.w};
  uint4v H, L;
#pragma unroll
  for (int i = 0; i < 4; ++i) {
    unsigned int u0 = __float_as_uint(f[2 * i]);
    unsigned int u1 = __float_as_uint(f[2 * i + 1]);
    H[i] = (u0 >> 16) | (u1 & 0xffff0000u);
    float l0 = f[2 * i]     - __uint_as_float(u0 & 0xffff0000u);
    float l1 = f[2 * i + 1] - __uint_as_float(u1 & 0xffff0000u);
    L[i] = (__float_as_uint(l0) >> 16) | (__float_as_uint(l1) & 0xffff0000u);
  }
  hi = __builtin_bit_cast(short8v, H);
  lo = __builtin_bit_cast(short8v, L);
}

__device__ inline ushort f2bf_rne(float x) {
  unsigned int u = __float_as_uint(x);
  unsigned int r = u + 0x7fffu + ((u >> 16) & 1u);
  return (ushort)(r >> 16);
}

__device__ inline float bf2f(unsigned short v) {
  return __uint_as_float((unsigned int)v << 16);
}

__device__ inline void gload_lds16(const float* gp, float* lp) {
  __builtin_amdgcn_global_load_lds(
      (const __attribute__((address_space(1))) void*)gp,
      (__attribute__((address_space(3))) void*)lp, 16, 0, 0);
}

// ---------------- prep: zero packed + convert W1/W2 to split-bf16 ------------

__global__ void k_prep(const float* __restrict__ W1, ushort* __restrict__ b1hi,
                       ushort* __restrict__ b1lo, const float* __restrict__ W2,
                       ushort* __restrict__ b2hi, ushort* __restrict__ b2lo,
                       unsigned long long* __restrict__ packed) {
  int id = blockIdx.x * 256 + threadIdx.x;
  if (id < NND) packed[id] = 0ull;
  const float* B; ushort *bhi, *blo; int NC;
  if (id < FIN * HID) { B = W1; bhi = b1hi; blo = b1lo; NC = HID; }
  else {
    id -= FIN * HID;
    if (id >= HID * ENC) return;
    B = W2; bhi = b2hi; blo = b2lo; NC = ENC;
  }
  int k = id / NC, c = id % NC;
  float x = B[id];
  unsigned int u = __float_as_uint(x);
  ushort h = (ushort)(u >> 16);
  float lo = x - __uint_as_float(u & 0xffff0000u);
  ushort l = (ushort)(__float_as_uint(lo) >> 16);
  size_t o = ((size_t)(k >> 3) * NC + c) * 8 + (k & 7);
  bhi[o] = h;
  blo[o] = l;
}

// ---------------- degree + rank: ONE packed 64-bit atomic per edge -----------

__global__ void k_deg_rank(const int* __restrict__ dst, const float* __restrict__ ppmi,
                           unsigned long long* __restrict__ packed,
                           int* __restrict__ rank) {
  int e = blockIdx.x * blockDim.x + threadIdx.x;
  if (e >= NED) return;
  int d = dst[e];
  unsigned int fx = (unsigned int)(ppmi[e] * 1073741824.0f + 0.5f);
  unsigned long long v = (1ull << 40) | (unsigned long long)fx;
  unsigned long long old = atomicAdd(&packed[d], v);
  rank[e] = (int)(old >> 40);
}

// ---------------- dinv + scan_a fused (per-node pass) ------------------------

__global__ void k_dinv_scan(const unsigned long long* __restrict__ packed,
                            float* __restrict__ dinv_g, float* __restrict__ dinv_p,
                            int* __restrict__ psum) {
  __shared__ int s[SCAN_BS];
  int t = threadIdx.x, i = blockIdx.x * SCAN_BS + t;
  int cnt = 0;
  if (i < NND) {
    unsigned long long pk = packed[i];
    cnt = (int)(pk >> 40);
    float dp = (float)(pk & 0xFFFFFFFFFFull) * (1.0f / 1073741824.0f);
    dinv_g[i] = 1.0f / sqrtf((float)cnt + 1.0f);
    dinv_p[i] = 1.0f / sqrtf(dp + 1.0f);
  }
  s[t] = cnt;
  __syncthreads();
  for (int o = SCAN_BS / 2; o; o >>= 1) {
    if (t < o) s[t] += s[t + o];
    __syncthreads();
  }
  if (t == 0) psum[blockIdx.x] = s[0];
}

__global__ void k_scan_b(int* __restrict__ psum) {
  __shared__ int s[512];
  int t = threadIdx.x;
  int v = (t < NBS) ? psum[t] : 0;
  s[t] = v;
  __syncthreads();
  for (int o = 1; o < 512; o <<= 1) {
    int add = (t >= o) ? s[t - o] : 0;
    __syncthreads();
    s[t] += add;
    __syncthreads();
  }
  if (t < NBS) psum[t] = s[t] - v;   // exclusive
}

__global__ void k_scan_c(const unsigned long long* __restrict__ packed,
                         const int* __restrict__ psum, int* __restrict__ row_ptr) {
  __shared__ int s[SCAN_BS];
  int t = threadIdx.x, i = blockIdx.x * SCAN_BS + t;
  int v = (i < NND) ? (int)(packed[i] >> 40) : 0;
  s[t] = v;
  __syncthreads();
  for (int o = 1; o < SCAN_BS; o <<= 1) {
    int add = (t >= o) ? s[t - o] : 0;
    __syncthreads();
    s[t] += add;
    __syncthreads();
  }
  if (i < NND) row_ptr[i] = psum[blockIdx.x] + s[t] - v;
  if (i == NND - 1) row_ptr[NND] = psum[blockIdx.x] + s[t];
}

// ---------------- CSR scatter: 8B record {src, gn_bf16|pn_bf16<<16} ----------

__global__ void k_scatter(const int* __restrict__ src, const int* __restrict__ dst,
                          const float* __restrict__ ppmi,
                          const int* __restrict__ row_ptr, const int* __restrict__ rank,
                          const float* __restrict__ dinv_g, const float* __restrict__ dinv_p,
                          int2* __restrict__ csr) {
  int e = blockIdx.x * blockDim.x + threadIdx.x;
  if (e >= NED) return;
  int s = src[e], d = dst[e];
  int pos = row_ptr[d] + rank[e];
  ushort gn = f2bf_rne(dinv_g[s] * dinv_g[d]);
  ushort pn = f2bf_rne(dinv_p[s] * ppmi[e] * dinv_p[d]);
  int2 rec;
  rec.x = s;
  rec.y = (int)gn | ((int)pn << 16);
  csr[pos] = rec;
}

// ---------------- GEMM1: h_linb(bf16) = x @ W1, LDS-staged split-bf16 MFMA ---
// 128x128 tile, BK=32, 4 waves (2x2). A fp32 -> LDS via global_load_lds w=16,
// double-buffered; 16B-chunk XOR swizzle on global source and ds_read.
// launch_bounds(256,3): VGPR budget 170 — spill-free (R10's (256,4) spilled).

__global__ __launch_bounds__(256, 3) void gemm1_lds(
    const float* __restrict__ A, const ushort* __restrict__ Bhi,
    const ushort* __restrict__ Blo, ushort* __restrict__ C) {
  __shared__ float At[2][128 * 32];
  const int tid = threadIdx.x;
  const int lane = tid & 63;
  const int w = tid >> 6;
  const int wr = w >> 1, wc = w & 1;
  const int g = lane >> 4;
  const int l16 = lane & 15;
  const int row_base = blockIdx.x * 128;

  size_t srow[4]; int scol[4];
  {
    int e = w * 256 + lane * 4;
#pragma unroll
    for (int i = 0; i < 4; ++i) {
      int ee = e + i * 1024;
      int r = ee >> 5;
      int chunk_lds = (ee >> 2) & 7;
      int chunk_g = chunk_lds ^ (r & 7);
      int rr = row_base + r; if (rr >= NND) rr = NND - 1;
      srow[i] = (size_t)rr * FIN;
      scol[i] = chunk_g * 4;
    }
  }

  int coln[4];
#pragma unroll
  for (int n = 0; n < 4; ++n) coln[n] = wc * 64 + n * 16 + l16;
  int arow_l[4];
#pragma unroll
  for (int m = 0; m < 4; ++m) arow_l[m] = wr * 64 + m * 16 + l16;

  f32x4 acc[4][4] = {};

#pragma unroll
  for (int i = 0; i < 4; ++i)
    gload_lds16(A + srow[i] + 0 + scol[i], &At[0][w * 256 + i * 1024]);
  __syncthreads();

  for (int t = 0; t < FIN / 32; ++t) {
    const int cur = t & 1;
    if (t + 1 < FIN / 32) {
      const int k0n = (t + 1) * 32;
#pragma unroll
      for (int i = 0; i < 4; ++i)
        gload_lds16(A + srow[i] + k0n + scol[i], &At[cur ^ 1][w * 256 + i * 1024]);
    }

    short8v ah[4], al[4];
#pragma unroll
    for (int m = 0; m < 4; ++m) {
      int r = arow_l[m];
      int c0 = (((g * 2)     ^ (r & 7)) << 2);
      int c1 = (((g * 2 + 1) ^ (r & 7)) << 2);
      float4 a0 = *(const float4*)&At[cur][r * 32 + c0];
      float4 a1 = *(const float4*)&At[cur][r * 32 + c1];
      split8(a0, a1, ah[m], al[m]);
    }

    short8v bh[4], bl[4];
    const int kc = t * 4 + g;
#pragma unroll
    for (int n = 0; n < 4; ++n) {
      size_t off = ((size_t)kc * HID + coln[n]) * 8;
      bh[n] = *(const short8v*)(Bhi + off);
      bl[n] = *(const short8v*)(Blo + off);
    }

#pragma unroll
    for (int m = 0; m < 4; ++m)
#pragma unroll
      for (int n = 0; n < 4; ++n) {
        acc[m][n] = __builtin_amdgcn_mfma_f32_16x16x32_bf16(ah[m], bh[n], acc[m][n], 0, 0, 0);
        acc[m][n] = __builtin_amdgcn_mfma_f32_16x16x32_bf16(al[m], bh[n], acc[m][n], 0, 0, 0);
        acc[m][n] = __builtin_amdgcn_mfma_f32_16x16x32_bf16(ah[m], bl[n], acc[m][n], 0, 0, 0);
      }

    __syncthreads();
  }

  // C/D layout: col = lane&15, row = (lane>>4)*4 + reg; wave offset wr*64 included
#pragma unroll
  for (int m = 0; m < 4; ++m)
#pragma unroll
    for (int i = 0; i < 4; ++i) {
      int r = row_base + wr * 64 + m * 16 + g * 4 + i;
      if (r < NND) {
#pragma unroll
        for (int n = 0; n < 4; ++n)
          C[(size_t)r * HID + coln[n]] = f2bf_rne(acc[m][n][i]);
      }
    }
}

// ---------------- GEMM2: h2b(bf16) = [hg;hp] @ W2, register-A bf16 -----------
// launch_bounds(256,4): VGPR budget 128 — spill-free (R10's (256,6) spilled).

template<int WR>
__global__ __launch_bounds__(256, 4) void gemm2_split(
    const ushort* __restrict__ As, const ushort* __restrict__ Bhi,
    const ushort* __restrict__ Blo, ushort* __restrict__ C,
    int M, int K, int Nc) {
  const int lane = threadIdx.x & 63;
  const int w = threadIdx.x >> 6;
  const int g = lane >> 4;
  const int l16 = lane & 15;
  const int row_base = blockIdx.x * (WR * 64) + w * 64;

  size_t arow[4];
#pragma unroll
  for (int m = 0; m < 4; ++m) {
    int r = row_base + m * 16 + l16;
    if (r >= M) r = M - 1;
    arow[m] = (size_t)r * K;
  }
  int coln[4];
#pragma unroll
  for (int n = 0; n < 4; ++n) coln[n] = n * 16 + l16;

  f32x4 acc[4][4] = {};

  for (int k0 = 0; k0 < K; k0 += 32) {
    short8v ah[4];
#pragma unroll
    for (int m = 0; m < 4; ++m)
      ah[m] = *(const short8v*)(As + arow[m] + k0 + g * 8);
    short8v bh[4], bl[4];
    const int kc = (k0 >> 3) + g;
#pragma unroll
    for (int n = 0; n < 4; ++n) {
      size_t off = ((size_t)kc * Nc + coln[n]) * 8;
      bh[n] = *(const short8v*)(Bhi + off);
      bl[n] = *(const short8v*)(Blo + off);
    }
#pragma unroll
    for (int m = 0; m < 4; ++m)
#pragma unroll
      for (int n = 0; n < 4; ++n) {
        acc[m][n] = __builtin_amdgcn_mfma_f32_16x16x32_bf16(ah[m], bh[n], acc[m][n], 0, 0, 0);
        acc[m][n] = __builtin_amdgcn_mfma_f32_16x16x32_bf16(ah[m], bl[n], acc[m][n], 0, 0, 0);
      }
  }

#pragma unroll
  for (int m = 0; m < 4; ++m)
#pragma unroll
    for (int i = 0; i < 4; ++i) {
      int r = row_base + m * 16 + g * 4 + i;
      if (r < M) {
#pragma unroll
        for (int n = 0; n < 4; ++n) {
          int c = coln[n];
          size_t o = (r < NND) ? ((size_t)r * 128 + c)
                               : ((size_t)(r - NND) * 128 + 64 + c);
          C[o] = f2bf_rne(acc[m][n][i]);
        }
      }
    }
}

// ---------------- layer-1 aggregation: bf16 gathers, 4 edges in flight -------

__global__ __launch_bounds__(256) void k_agg1(
    const ushort* __restrict__ hlinb, const int* __restrict__ row_ptr,
    const int2* __restrict__ csr,
    const float* __restrict__ dinv_g, const float* __restrict__ dinv_p,
    const float* __restrict__ b1, ushort* __restrict__ hhs) {
  int wid = (blockIdx.x * blockDim.x + threadIdx.x) >> 6;
  int lane = threadIdx.x & 63;
  if (wid >= NND) return;
  const int gp = lane >> 4;
  const int t  = lane & 15;
  float sg = dinv_g[wid]; sg *= sg;
  float sp = dinv_p[wid]; sp *= sp;

  float ag[8] = {}, ap[8] = {};
  if (gp == 0) {
    ushort8v v = *(const ushort8v*)(hlinb + (size_t)wid * HID + 8 * t);
#pragma unroll
    for (int i = 0; i < 8; ++i) {
      float f = bf2f(v[i]);
      ag[i] = f * sg; ap[i] = f * sp;
    }
  }
  int e0 = row_ptr[wid], e1 = row_ptr[wid + 1];
  int k = e0 + gp;
  if (k < e1) {
    int2 rec = csr[k];
    while (true) {
      int kn = k + 4;
      int2 nrec = csr[kn < e1 ? kn : k];      // clamped prefetch
      float wg = bf2f((ushort)(rec.y & 0xffff));
      float wp = bf2f((ushort)((unsigned)rec.y >> 16));
      ushort8v u = *(const ushort8v*)(hlinb + (size_t)rec.x * HID + 8 * t);
#pragma unroll
      for (int i = 0; i < 8; ++i) {
        float f = bf2f(u[i]);
        ag[i] = fmaf(f, wg, ag[i]);
        ap[i] = fmaf(f, wp, ap[i]);
      }
      if (kn >= e1) break;
      k = kn; rec = nrec;
    }
  }
#pragma unroll
  for (int i = 0; i < 8; ++i) {
    ag[i] += __shfl_xor(ag[i], 32); ap[i] += __shfl_xor(ap[i], 32);
    ag[i] += __shfl_xor(ag[i], 16); ap[i] += __shfl_xor(ap[i], 16);
  }

  float bb[8];
  *(float4*)&bb[0] = *(const float4*)(b1 + 8 * t);
  *(float4*)&bb[4] = *(const float4*)(b1 + 8 * t + 4);
  if (gp == 0 || gp == 2) {
    ushort8v outv;
#pragma unroll
    for (int i = 0; i < 8; ++i) {
      float v = (gp == 0) ? fmaxf(ag[i] + bb[i], 0.f) : fmaxf(ap[i] + bb[i], 0.f);
      outv[i] = f2bf_rne(v);
    }
    size_t row = (gp == 0) ? (size_t)wid : (size_t)(NND + wid);
    *(ushort8v*)(hhs + row * HID + 8 * t) = outv;
  }
}

// ---------------- layer-2 aggregation + attention -> emb ---------------------

__global__ __launch_bounds__(256) void k_agg2(
    const ushort* __restrict__ h2b, const int* __restrict__ row_ptr,
    const int2* __restrict__ csr,
    const float* __restrict__ dinv_g, const float* __restrict__ dinv_p,
    const float* __restrict__ b2, const float* __restrict__ att_w,
    const float* __restrict__ att_b, float* __restrict__ out_emb) {
  int wid = (blockIdx.x * blockDim.x + threadIdx.x) >> 6;
  int lane = threadIdx.x & 63;
  if (wid >= NND) return;
  const int gp = lane >> 4;
  const int t  = lane & 15;
  const int br = t >> 3;            // 0 = g branch, 1 = p branch
  const int f0 = (t & 7) * 8;       // feature base within branch
  float sg = dinv_g[wid]; sg *= sg;
  float sp = dinv_p[wid]; sp *= sp;
  const float sw = br ? sp : sg;

  float acc[8] = {};
  if (gp == 0) {
    ushort8v v = *(const ushort8v*)(h2b + (size_t)wid * 128 + 8 * t);
#pragma unroll
    for (int i = 0; i < 8; ++i) acc[i] = bf2f(v[i]) * sw;
  }
  int e0 = row_ptr[wid], e1 = row_ptr[wid + 1];
  int k = e0 + gp;
  if (k < e1) {
    int2 rec = csr[k];
    while (true) {
      int kn = k + 4;
      int2 nrec = csr[kn < e1 ? kn : k];
      float w = br ? bf2f((ushort)((unsigned)rec.y >> 16))
                   : bf2f((ushort)(rec.y & 0xffff));
      ushort8v u = *(const ushort8v*)(h2b + (size_t)rec.x * 128 + 8 * t);
#pragma unroll
      for (int i = 0; i < 8; ++i) acc[i] = fmaf(bf2f(u[i]), w, acc[i]);
      if (kn >= e1) break;
      k = kn; rec = nrec;
    }
  }
#pragma unroll
  for (int i = 0; i < 8; ++i) {
    acc[i] += __shfl_xor(acc[i], 32);
    acc[i] += __shfl_xor(acc[i], 16);
  }

  float bb[8];
  *(float4*)&bb[0] = *(const float4*)(b2 + f0);
  *(float4*)&bb[4] = *(const float4*)(b2 + f0 + 4);
  float v[8];
#pragma unroll
  for (int i = 0; i < 8; ++i) v[i] = acc[i] + bb[i];

  float aw[8];
  *(float4*)&aw[0] = *(const float4*)(att_w + f0);
  *(float4*)&aw[4] = *(const float4*)(att_w + f0 + 4);
  float part = 0.f;
#pragma unroll
  for (int i = 0; i < 8; ++i) part = fmaf(v[i], aw[i], part);
  part += __shfl_xor(part, 4);
  part += __shfl_xor(part, 2);
  part += __shfl_xor(part, 1);
  float other = __shfl_xor(part, 8);
  float ab = att_b[0];
  float lg = (br ? other : part) + ab;
  float lp = (br ? part : other) + ab;
  float mx = fmaxf(lg, lp);
  float eg = expf(lg - mx), ep2 = expf(lp - mx);
  float wsm = eg / (eg + ep2);          // weight of g branch

  float ov[8];
#pragma unroll
  for (int i = 0; i < 8; ++i) ov[i] = __shfl_xor(v[i], 8);
  if (gp == 0 && br == 0) {
    float4* dst = (float4*)(out_emb + (size_t)wid * 64 + f0);
    float4 o0, o1;
    o0.x = wsm * v[0] + (1.f - wsm) * ov[0];
    o0.y = wsm * v[1] + (1.f - wsm) * ov[1];
    o0.z = wsm * v[2] + (1.f - wsm) * ov[2];
    o0.w = wsm * v[3] + (1.f - wsm) * ov[3];
    o1.x = wsm * v[4] + (1.f - wsm) * ov[4];
    o1.y = wsm * v[5] + (1.f - wsm) * ov[5];
    o1.z = wsm * v[6] + (1.f - wsm) * ov[6];
    o1.w = wsm * v[7] + (1.f - wsm) * ov[7];
    dst[0] = o0;
    dst[1] = o1;
  }
}

// ---------------- class + domain heads --------------

__global__ __launch_bounds__(128) void k_head(
    const float* __restrict__ emb,
    const float* __restrict__ cls_w, const float* __restrict__ cls_b,
    const float* __restrict__ dw1, const float* __restrict__ db1,
    const float* __restrict__ dw2, const float* __restrict__ db2,
    float* __restrict__ out_cls, float* __restrict__ out_dom) {
  __shared__ float se[128 * 65];
  const int t = threadIdx.x;
  const int base = blockIdx.x * 128;
  for (int c = 0; c < 64; ++c) {
    int idx = c * 128 + t;
    int nl = idx >> 6, k = idx & 63;
    size_t g = (size_t)base * ENC + idx;
    float v = (g < (size_t)NND * ENC) ? emb[g] : 0.f;
    se[nl * 65 + k] = v;
  }
  __syncthreads();

  int node = base + t;
  float c[NCLS], hd[DOM];
#pragma unroll
  for (int j = 0; j < NCLS; ++j) c[j] = cls_b[j];
#pragma unroll
  for (int j = 0; j < DOM; ++j) hd[j] = db1[j];

  for (int k = 0; k < ENC; ++k) {
    float ev = se[t * 65 + k];
#pragma unroll
    for (int j = 0; j < NCLS; ++j) c[j] += ev * cls_w[k * NCLS + j];
#pragma unroll
    for (int j = 0; j < DOM; ++j) hd[j] += ev * dw1[k * DOM + j];
  }
  float d0 = db2[0], d1 = db2[1];
#pragma unroll
  for (int j = 0; j < DOM; ++j) {
    float hv = fmaxf(hd[j], 0.f);
    d0 += hv * dw2[j * 2];
    d1 += hv * dw2[j * 2 + 1];
  }
  if (node < NND) {
#pragma unroll
    for (int j = 0; j < NCLS; ++j) out_cls[(size_t)node * NCLS + j] = c[j];
    out_dom[(size_t)node * 2]     = d0;
    out_dom[(size_t)node * 2 + 1] = d1;
  }
}

// ---------------- host ----------------

extern "C" void kernel_launch(void* const* d_in, const int* in_sizes, int n_in,
                              void* d_out, int out_size, void* d_ws, size_t ws_size,
                              hipStream_t stream) {
  const float* x     = (const float*)d_in[0];
  const int*   ei    = (const int*)d_in[1];
  const float* ppmi  = (const float*)d_in[2];
  const float* W1    = (const float*)d_in[4];
  const float* b1    = (const float*)d_in[5];
  const float* W2    = (const float*)d_in[6];
  const float* b2    = (const float*)d_in[7];
  const float* att_w = (const float*)d_in[8];
  const float* att_b = (const float*)d_in[9];
  const float* cls_w = (const float*)d_in[10];
  const float* cls_b = (const float*)d_in[11];
  const float* dw1   = (const float*)d_in[12];
  const float* db1   = (const float*)d_in[13];
  const float* dw2   = (const float*)d_in[14];
  const float* db2   = (const float*)d_in[15];

  const int* src = ei;
  const int* dst = ei + NED;

  uintptr_t p = (uintptr_t)d_ws;
  auto alloc = [&](size_t bytes) -> void* {
    void* r = (void*)p;
    p += (bytes + 255) & ~(size_t)255;
    return r;
  };
  unsigned long long* packed = (unsigned long long*)alloc((size_t)NND * 8);
  int*    rank    = (int*)   alloc((size_t)NED * 4);
  int*    row_ptr = (int*)   alloc((size_t)(NND + 1) * 4);
  int*    psum    = (int*)   alloc((size_t)NBS * 4);
  float*  dinv_g  = (float*) alloc((size_t)NND * 4);
  float*  dinv_p  = (float*) alloc((size_t)NND * 4);
  int2*   csr     = (int2*)  alloc((size_t)NED * 8);
  ushort* b1hi    = (ushort*)alloc((size_t)FIN * HID * 2);
  ushort* b1lo    = (ushort*)alloc((size_t)FIN * HID * 2);
  ushort* b2hi    = (ushort*)alloc((size_t)HID * ENC * 2);
  ushort* b2lo    = (ushort*)alloc((size_t)HID * ENC * 2);
  ushort* h2b     = (ushort*)alloc((size_t)NND * HID * 2);        // bf16 h2 pair
  ushort* hhs     = (ushort*)alloc((size_t)2 * NND * HID * 2);    // bf16 hg|hp

  float* out_emb = (float*)d_out;
  float* out_cls = (float*)d_out + (size_t)NND * ENC;
  float* out_dom = (float*)d_out + (size_t)NND * (ENC + NCLS);

  // bf16 h_lin lives in the d_out emb region (NND*128*2B == NND*64*4B exactly);
  // dead before agg2 overwrites the region with emb.
  ushort* h_linb = (ushort*)d_out;

  // ---- prep (zero packed + weight conversion, one launch) ----
  k_prep<<<(NND + 255) / 256, 256, 0, stream>>>(W1, b1hi, b1lo, W2, b2hi, b2lo,
                                                packed);

  // ---- graph preprocessing ----
  k_deg_rank<<<NED / 256, 256, 0, stream>>>(dst, ppmi, packed, rank);
  k_dinv_scan<<<NBS, SCAN_BS, 0, stream>>>(packed, dinv_g, dinv_p, psum);
  k_scan_b<<<1, 512, 0, stream>>>(psum);
  k_scan_c<<<NBS, SCAN_BS, 0, stream>>>(packed, psum, row_ptr);
  k_scatter<<<NED / 256, 256, 0, stream>>>(src, dst, ppmi, row_ptr, rank,
                                           dinv_g, dinv_p, csr);

  // ---- encoder ----
  gemm1_lds<<<(NND + 127) / 128, 256, 0, stream>>>(x, b1hi, b1lo, h_linb);
  k_agg1<<<(NND * 64) / 256, 256, 0, stream>>>(h_linb, row_ptr, csr,
                                               dinv_g, dinv_p, b1, hhs);
  gemm2_split<4><<<(2 * NND + 255) / 256, 256, 0, stream>>>(
      hhs, b2hi, b2lo, h2b, 2 * NND, HID, ENC);
  k_agg2<<<(NND * 64) / 256, 256, 0, stream>>>(h2b, row_ptr, csr,
                                               dinv_g, dinv_p, b2, att_w, att_b, out_emb);

  // ---- heads ----
  k_head<<<(NND + 127) / 128, 128, 0, stream>>>(out_emb, cls_w, cls_b, dw1, db1,
                                                dw2, db2, out_cls, out_dom);
}

// Round 12
// 427.126 us; speedup vs baseline: 1.2821x; 1.0365x over previous
//
#include <hip/hip_runtime.h>
#include <math.h>
#include <stdint.h>

#define NND  100000   // nodes
#define NED  1600000  // edges (without self loops)
#define FIN  512
#define HID  128
#define ENC  64
#define NCLS 10
#define DOM  40

#define SCAN_BS 256
#define NBS ((NND + SCAN_BS - 1) / SCAN_BS)   // 391

typedef __attribute__((ext_vector_type(8))) short short8v;
typedef __attribute__((ext_vector_type(8))) unsigned short ushort8v;
typedef __attribute__((ext_vector_type(4))) float f32x4;
typedef __attribute__((ext_vector_type(4))) unsigned int uint4v;

// ---------------- helpers ----------------

__device__ inline void split8(const float4 a, const float4 b,
                              short8v& hi, short8v& lo) {
  float f[8] = {a.x, a.y, a.z, a.w, b.x, b.y, b.z, b.w};
  uint4v H, L;
#pragma unroll
  for (int i = 0; i < 4; ++i) {
    unsigned int u0 = __float_as_uint(f[2 * i]);
    unsigned int u1 = __float_as_uint(f[2 * i + 1]);
    H[i] = (u0 >> 16) | (u1 & 0xffff0000u);
    float l0 = f[2 * i]     - __uint_as_float(u0 & 0xffff0000u);
    float l1 = f[2 * i + 1] - __uint_as_float(u1 & 0xffff0000u);
    L[i] = (__float_as_uint(l0) >> 16) | (__float_as_uint(l1) & 0xffff0000u);
  }
  hi = __builtin_bit_cast(short8v, H);
  lo = __builtin_bit_cast(short8v, L);
}

__device__ inline ushort f2bf_rne(float x) {
  unsigned int u = __float_as_uint(x);
  unsigned int r = u + 0x7fffu + ((u >> 16) & 1u);
  return (ushort)(r >> 16);
}

__device__ inline float bf2f(unsigned short v) {
  return __uint_as_float((unsigned int)v << 16);
}

__device__ inline void gload_lds16(const float* gp, float* lp) {
  __builtin_amdgcn_global_load_lds(
      (const __attribute__((address_space(1))) void*)gp,
      (__attribute__((address_space(3))) void*)lp, 16, 0, 0);
}

// ---------------- prep: zero packed + convert W1(RNE) / W2(split) ------------
// W1 -> b1hi bf16-RNE only (gemm1 is 2-term: x_hi*W1h + x_lo*W1h).
// W2 -> trunc hi + residual lo (gemm2 keeps the W-correction term).

__global__ void k_prep(const float* __restrict__ W1, ushort* __restrict__ b1hi,
                       const float* __restrict__ W2,
                       ushort* __restrict__ b2hi, ushort* __restrict__ b2lo,
                       unsigned int* __restrict__ packed) {
  int id = blockIdx.x * 256 + threadIdx.x;
  if (id < NND) packed[id] = 0u;
  if (id < FIN * HID) {
    int k = id / HID, c = id % HID;
    size_t o = ((size_t)(k >> 3) * HID + c) * 8 + (k & 7);
    b1hi[o] = f2bf_rne(W1[id]);
  } else {
    int id2 = id - FIN * HID;
    if (id2 >= HID * ENC) return;
    int k = id2 / ENC, c = id2 % ENC;
    float x = W2[id2];
    unsigned int u = __float_as_uint(x);
    ushort h = (ushort)(u >> 16);
    float lo = x - __uint_as_float(u & 0xffff0000u);
    ushort l = (ushort)(__float_as_uint(lo) >> 16);
    size_t o = ((size_t)(k >> 3) * ENC + c) * 8 + (k & 7);
    b2hi[o] = h;
    b2lo[o] = l;
  }
}

// ---------------- degree + rank: ONE packed 32-bit atomic per edge -----------
// packed[d]: bits [25,32) = count (deg <= 127; Poisson(16) tail ~1e-16),
// bits [0,25) = sum(ppmi) in 2^-18 fixed point (max 128 > 127*1.0).

__global__ void k_deg_rank(const int* __restrict__ dst, const float* __restrict__ ppmi,
                           unsigned int* __restrict__ packed,
                           ushort* __restrict__ rank) {
  int e = blockIdx.x * blockDim.x + threadIdx.x;
  if (e >= NED) return;
  int d = dst[e];
  unsigned int fx = (unsigned int)(ppmi[e] * 262144.0f + 0.5f);  // 2^18 scale
  unsigned int v = (1u << 25) | fx;
  unsigned int old = atomicAdd(&packed[d], v);
  rank[e] = (ushort)(old >> 25);
}

// ---------------- dinv + scan_a fused (per-node pass) ------------------------

__global__ void k_dinv_scan(const unsigned int* __restrict__ packed,
                            float* __restrict__ dinv_g, float* __restrict__ dinv_p,
                            int* __restrict__ psum) {
  __shared__ int s[SCAN_BS];
  int t = threadIdx.x, i = blockIdx.x * SCAN_BS + t;
  int cnt = 0;
  if (i < NND) {
    unsigned int pk = packed[i];
    cnt = (int)(pk >> 25);
    float dp = (float)(pk & 0x1FFFFFFu) * (1.0f / 262144.0f);
    dinv_g[i] = 1.0f / sqrtf((float)cnt + 1.0f);
    dinv_p[i] = 1.0f / sqrtf(dp + 1.0f);
  }
  s[t] = cnt;
  __syncthreads();
  for (int o = SCAN_BS / 2; o; o >>= 1) {
    if (t < o) s[t] += s[t + o];
    __syncthreads();
  }
  if (t == 0) psum[blockIdx.x] = s[0];
}

__global__ void k_scan_b(int* __restrict__ psum) {
  __shared__ int s[512];
  int t = threadIdx.x;
  int v = (t < NBS) ? psum[t] : 0;
  s[t] = v;
  __syncthreads();
  for (int o = 1; o < 512; o <<= 1) {
    int add = (t >= o) ? s[t - o] : 0;
    __syncthreads();
    s[t] += add;
    __syncthreads();
  }
  if (t < NBS) psum[t] = s[t] - v;   // exclusive
}

__global__ void k_scan_c(const unsigned int* __restrict__ packed,
                         const int* __restrict__ psum, int* __restrict__ row_ptr) {
  __shared__ int s[SCAN_BS];
  int t = threadIdx.x, i = blockIdx.x * SCAN_BS + t;
  int v = (i < NND) ? (int)(packed[i] >> 25) : 0;
  s[t] = v;
  __syncthreads();
  for (int o = 1; o < SCAN_BS; o <<= 1) {
    int add = (t >= o) ? s[t - o] : 0;
    __syncthreads();
    s[t] += add;
    __syncthreads();
  }
  if (i < NND) row_ptr[i] = psum[blockIdx.x] + s[t] - v;
  if (i == NND - 1) row_ptr[NND] = psum[blockIdx.x] + s[t];
}

// ---------------- CSR scatter: 8B record {src, gn_bf16|pn_bf16<<16} ----------

__global__ void k_scatter(const int* __restrict__ src, const int* __restrict__ dst,
                          const float* __restrict__ ppmi,
                          const int* __restrict__ row_ptr, const ushort* __restrict__ rank,
                          const float* __restrict__ dinv_g, const float* __restrict__ dinv_p,
                          int2* __restrict__ csr) {
  int e = blockIdx.x * blockDim.x + threadIdx.x;
  if (e >= NED) return;
  int s = src[e], d = dst[e];
  int pos = row_ptr[d] + (int)rank[e];
  ushort gn = f2bf_rne(dinv_g[s] * dinv_g[d]);
  ushort pn = f2bf_rne(dinv_p[s] * ppmi[e] * dinv_p[d]);
  int2 rec;
  rec.x = s;
  rec.y = (int)gn | ((int)pn << 16);
  csr[pos] = rec;
}

// ---------------- GEMM1: h_linb(bf16) = x @ W1, LDS-staged 2-term MFMA -------
// 128x128 tile, BK=32, 4 waves (2x2). A fp32 -> LDS via global_load_lds w=16,
// double-buffered; 16B-chunk XOR swizzle on global source and ds_read.
// 2-term: x_hi*W1h + x_lo*W1h (W1h is RNE bf16; W-lo correction dropped,
// error ~6.5e-4 rms in h_lin -> ~2e-4 rms in emb, within threshold budget).
// launch_bounds(256,3): VGPR budget 170 — spill-free.

__global__ __launch_bounds__(256, 3) void gemm1_lds(
    const float* __restrict__ A, const ushort* __restrict__ Bhi,
    ushort* __restrict__ C) {
  __shared__ float At[2][128 * 32];
  const int tid = threadIdx.x;
  const int lane = tid & 63;
  const int w = tid >> 6;
  const int wr = w >> 1, wc = w & 1;
  const int g = lane >> 4;
  const int l16 = lane & 15;
  const int row_base = blockIdx.x * 128;

  size_t srow[4]; int scol[4];
  {
    int e = w * 256 + lane * 4;
#pragma unroll
    for (int i = 0; i < 4; ++i) {
      int ee = e + i * 1024;
      int r = ee >> 5;
      int chunk_lds = (ee >> 2) & 7;
      int chunk_g = chunk_lds ^ (r & 7);
      int rr = row_base + r; if (rr >= NND) rr = NND - 1;
      srow[i] = (size_t)rr * FIN;
      scol[i] = chunk_g * 4;
    }
  }

  int coln[4];
#pragma unroll
  for (int n = 0; n < 4; ++n) coln[n] = wc * 64 + n * 16 + l16;
  int arow_l[4];
#pragma unroll
  for (int m = 0; m < 4; ++m) arow_l[m] = wr * 64 + m * 16 + l16;

  f32x4 acc[4][4] = {};

#pragma unroll
  for (int i = 0; i < 4; ++i)
    gload_lds16(A + srow[i] + 0 + scol[i], &At[0][w * 256 + i * 1024]);
  __syncthreads();

  for (int t = 0; t < FIN / 32; ++t) {
    const int cur = t & 1;
    if (t + 1 < FIN / 32) {
      const int k0n = (t + 1) * 32;
#pragma unroll
      for (int i = 0; i < 4; ++i)
        gload_lds16(A + srow[i] + k0n + scol[i], &At[cur ^ 1][w * 256 + i * 1024]);
    }

    short8v ah[4], al[4];
#pragma unroll
    for (int m = 0; m < 4; ++m) {
      int r = arow_l[m];
      int c0 = (((g * 2)     ^ (r & 7)) << 2);
      int c1 = (((g * 2 + 1) ^ (r & 7)) << 2);
      float4 a0 = *(const float4*)&At[cur][r * 32 + c0];
      float4 a1 = *(const float4*)&At[cur][r * 32 + c1];
      split8(a0, a1, ah[m], al[m]);
    }

    short8v bh[4];
    const int kc = t * 4 + g;
#pragma unroll
    for (int n = 0; n < 4; ++n)
      bh[n] = *(const short8v*)(Bhi + ((size_t)kc * HID + coln[n]) * 8);

#pragma unroll
    for (int m = 0; m < 4; ++m)
#pragma unroll
      for (int n = 0; n < 4; ++n) {
        acc[m][n] = __builtin_amdgcn_mfma_f32_16x16x32_bf16(ah[m], bh[n], acc[m][n], 0, 0, 0);
        acc[m][n] = __builtin_amdgcn_mfma_f32_16x16x32_bf16(al[m], bh[n], acc[m][n], 0, 0, 0);
      }

    __syncthreads();
  }

  // C/D layout: col = lane&15, row = (lane>>4)*4 + reg; wave offset wr*64 included
#pragma unroll
  for (int m = 0; m < 4; ++m)
#pragma unroll
    for (int i = 0; i < 4; ++i) {
      int r = row_base + wr * 64 + m * 16 + g * 4 + i;
      if (r < NND) {
#pragma unroll
        for (int n = 0; n < 4; ++n)
          C[(size_t)r * HID + coln[n]] = f2bf_rne(acc[m][n][i]);
      }
    }
}

// ---------------- GEMM2: h2b(bf16) = [hg;hp] @ W2, register-A bf16 -----------
// launch_bounds(256,4): VGPR budget 128 — spill-free.

template<int WR>
__global__ __launch_bounds__(256, 4) void gemm2_split(
    const ushort* __restrict__ As, const ushort* __restrict__ Bhi,
    const ushort* __restrict__ Blo, ushort* __restrict__ C,
    int M, int K, int Nc) {
  const int lane = threadIdx.x & 63;
  const int w = threadIdx.x >> 6;
  const int g = lane >> 4;
  const int l16 = lane & 15;
  const int row_base = blockIdx.x * (WR * 64) + w * 64;

  size_t arow[4];
#pragma unroll
  for (int m = 0; m < 4; ++m) {
    int r = row_base + m * 16 + l16;
    if (r >= M) r = M - 1;
    arow[m] = (size_t)r * K;
  }
  int coln[4];
#pragma unroll
  for (int n = 0; n < 4; ++n) coln[n] = n * 16 + l16;

  f32x4 acc[4][4] = {};

  for (int k0 = 0; k0 < K; k0 += 32) {
    short8v ah[4];
#pragma unroll
    for (int m = 0; m < 4; ++m)
      ah[m] = *(const short8v*)(As + arow[m] + k0 + g * 8);
    short8v bh[4], bl[4];
    const int kc = (k0 >> 3) + g;
#pragma unroll
    for (int n = 0; n < 4; ++n) {
      size_t off = ((size_t)kc * Nc + coln[n]) * 8;
      bh[n] = *(const short8v*)(Bhi + off);
      bl[n] = *(const short8v*)(Blo + off);
    }
#pragma unroll
    for (int m = 0; m < 4; ++m)
#pragma unroll
      for (int n = 0; n < 4; ++n) {
        acc[m][n] = __builtin_amdgcn_mfma_f32_16x16x32_bf16(ah[m], bh[n], acc[m][n], 0, 0, 0);
        acc[m][n] = __builtin_amdgcn_mfma_f32_16x16x32_bf16(ah[m], bl[n], acc[m][n], 0, 0, 0);
      }
  }

#pragma unroll
  for (int m = 0; m < 4; ++m)
#pragma unroll
    for (int i = 0; i < 4; ++i) {
      int r = row_base + m * 16 + g * 4 + i;
      if (r < M) {
#pragma unroll
        for (int n = 0; n < 4; ++n) {
          int c = coln[n];
          size_t o = (r < NND) ? ((size_t)r * 128 + c)
                               : ((size_t)(r - NND) * 128 + 64 + c);
          C[o] = f2bf_rne(acc[m][n][i]);
        }
      }
    }
}

// ---------------- layer-1 aggregation: bf16 gathers, 4 edges in flight -------

__global__ __launch_bounds__(256) void k_agg1(
    const ushort* __restrict__ hlinb, const int* __restrict__ row_ptr,
    const int2* __restrict__ csr,
    const float* __restrict__ dinv_g, const float* __restrict__ dinv_p,
    const float* __restrict__ b1, ushort* __restrict__ hhs) {
  int wid = (blockIdx.x * blockDim.x + threadIdx.x) >> 6;
  int lane = threadIdx.x & 63;
  if (wid >= NND) return;
  const int gp = lane >> 4;
  const int t  = lane & 15;
  float sg = dinv_g[wid]; sg *= sg;
  float sp = dinv_p[wid]; sp *= sp;

  float ag[8] = {}, ap[8] = {};
  if (gp == 0) {
    ushort8v v = *(const ushort8v*)(hlinb + (size_t)wid * HID + 8 * t);
#pragma unroll
    for (int i = 0; i < 8; ++i) {
      float f = bf2f(v[i]);
      ag[i] = f * sg; ap[i] = f * sp;
    }
  }
  int e0 = row_ptr[wid], e1 = row_ptr[wid + 1];
  int k = e0 + gp;
  if (k < e1) {
    int2 rec = csr[k];
    while (true) {
      int kn = k + 4;
      int2 nrec = csr[kn < e1 ? kn : k];      // clamped prefetch
      float wg = bf2f((ushort)(rec.y & 0xffff));
      float wp = bf2f((ushort)((unsigned)rec.y >> 16));
      ushort8v u = *(const ushort8v*)(hlinb + (size_t)rec.x * HID + 8 * t);
#pragma unroll
      for (int i = 0; i < 8; ++i) {
        float f = bf2f(u[i]);
        ag[i] = fmaf(f, wg, ag[i]);
        ap[i] = fmaf(f, wp, ap[i]);
      }
      if (kn >= e1) break;
      k = kn; rec = nrec;
    }
  }
#pragma unroll
  for (int i = 0; i < 8; ++i) {
    ag[i] += __shfl_xor(ag[i], 32); ap[i] += __shfl_xor(ap[i], 32);
    ag[i] += __shfl_xor(ag[i], 16); ap[i] += __shfl_xor(ap[i], 16);
  }

  float bb[8];
  *(float4*)&bb[0] = *(const float4*)(b1 + 8 * t);
  *(float4*)&bb[4] = *(const float4*)(b1 + 8 * t + 4);
  if (gp == 0 || gp == 2) {
    ushort8v outv;
#pragma unroll
    for (int i = 0; i < 8; ++i) {
      float v = (gp == 0) ? fmaxf(ag[i] + bb[i], 0.f) : fmaxf(ap[i] + bb[i], 0.f);
      outv[i] = f2bf_rne(v);
    }
    size_t row = (gp == 0) ? (size_t)wid : (size_t)(NND + wid);
    *(ushort8v*)(hhs + row * HID + 8 * t) = outv;
  }
}

// ---------------- layer-2 aggregation + attention -> emb ---------------------

__global__ __launch_bounds__(256) void k_agg2(
    const ushort* __restrict__ h2b, const int* __restrict__ row_ptr,
    const int2* __restrict__ csr,
    const float* __restrict__ dinv_g, const float* __restrict__ dinv_p,
    const float* __restrict__ b2, const float* __restrict__ att_w,
    const float* __restrict__ att_b, float* __restrict__ out_emb) {
  int wid = (blockIdx.x * blockDim.x + threadIdx.x) >> 6;
  int lane = threadIdx.x & 63;
  if (wid >= NND) return;
  const int gp = lane >> 4;
  const int t  = lane & 15;
  const int br = t >> 3;            // 0 = g branch, 1 = p branch
  const int f0 = (t & 7) * 8;       // feature base within branch
  float sg = dinv_g[wid]; sg *= sg;
  float sp = dinv_p[wid]; sp *= sp;
  const float sw = br ? sp : sg;

  float acc[8] = {};
  if (gp == 0) {
    ushort8v v = *(const ushort8v*)(h2b + (size_t)wid * 128 + 8 * t);
#pragma unroll
    for (int i = 0; i < 8; ++i) acc[i] = bf2f(v[i]) * sw;
  }
  int e0 = row_ptr[wid], e1 = row_ptr[wid + 1];
  int k = e0 + gp;
  if (k < e1) {
    int2 rec = csr[k];
    while (true) {
      int kn = k + 4;
      int2 nrec = csr[kn < e1 ? kn : k];
      float w = br ? bf2f((ushort)((unsigned)rec.y >> 16))
                   : bf2f((ushort)(rec.y & 0xffff));
      ushort8v u = *(const ushort8v*)(h2b + (size_t)rec.x * 128 + 8 * t);
#pragma unroll
      for (int i = 0; i < 8; ++i) acc[i] = fmaf(bf2f(u[i]), w, acc[i]);
      if (kn >= e1) break;
      k = kn; rec = nrec;
    }
  }
#pragma unroll
  for (int i = 0; i < 8; ++i) {
    acc[i] += __shfl_xor(acc[i], 32);
    acc[i] += __shfl_xor(acc[i], 16);
  }

  float bb[8];
  *(float4*)&bb[0] = *(const float4*)(b2 + f0);
  *(float4*)&bb[4] = *(const float4*)(b2 + f0 + 4);
  float v[8];
#pragma unroll
  for (int i = 0; i < 8; ++i) v[i] = acc[i] + bb[i];

  float aw[8];
  *(float4*)&aw[0] = *(const float4*)(att_w + f0);
  *(float4*)&aw[4] = *(const float4*)(att_w + f0 + 4);
  float part = 0.f;
#pragma unroll
  for (int i = 0; i < 8; ++i) part = fmaf(v[i], aw[i], part);
  part += __shfl_xor(part, 4);
  part += __shfl_xor(part, 2);
  part += __shfl_xor(part, 1);
  float other = __shfl_xor(part, 8);
  float ab = att_b[0];
  float lg = (br ? other : part) + ab;
  float lp = (br ? part : other) + ab;
  float mx = fmaxf(lg, lp);
  float eg = expf(lg - mx), ep2 = expf(lp - mx);
  float wsm = eg / (eg + ep2);          // weight of g branch

  float ov[8];
#pragma unroll
  for (int i = 0; i < 8; ++i) ov[i] = __shfl_xor(v[i], 8);
  if (gp == 0 && br == 0) {
    float4* dst = (float4*)(out_emb + (size_t)wid * 64 + f0);
    float4 o0, o1;
    o0.x = wsm * v[0] + (1.f - wsm) * ov[0];
    o0.y = wsm * v[1] + (1.f - wsm) * ov[1];
    o0.z = wsm * v[2] + (1.f - wsm) * ov[2];
    o0.w = wsm * v[3] + (1.f - wsm) * ov[3];
    o1.x = wsm * v[4] + (1.f - wsm) * ov[4];
    o1.y = wsm * v[5] + (1.f - wsm) * ov[5];
    o1.z = wsm * v[6] + (1.f - wsm) * ov[6];
    o1.w = wsm * v[7] + (1.f - wsm) * ov[7];
    dst[0] = o0;
    dst[1] = o1;
  }
}

// ---------------- class + domain heads --------------

__global__ __launch_bounds__(128) void k_head(
    const float* __restrict__ emb,
    const float* __restrict__ cls_w, const float* __restrict__ cls_b,
    const float* __restrict__ dw1, const float* __restrict__ db1,
    const float* __restrict__ dw2, const float* __restrict__ db2,
    float* __restrict__ out_cls, float* __restrict__ out_dom) {
  __shared__ float se[128 * 65];
  const int t = threadIdx.x;
  const int base = blockIdx.x * 128;
  for (int c = 0; c < 64; ++c) {
    int idx = c * 128 + t;
    int nl = idx >> 6, k = idx & 63;
    size_t g = (size_t)base * ENC + idx;
    float v = (g < (size_t)NND * ENC) ? emb[g] : 0.f;
    se[nl * 65 + k] = v;
  }
  __syncthreads();

  int node = base + t;
  float c[NCLS], hd[DOM];
#pragma unroll
  for (int j = 0; j < NCLS; ++j) c[j] = cls_b[j];
#pragma unroll
  for (int j = 0; j < DOM; ++j) hd[j] = db1[j];

  for (int k = 0; k < ENC; ++k) {
    float ev = se[t * 65 + k];
#pragma unroll
    for (int j = 0; j < NCLS; ++j) c[j] += ev * cls_w[k * NCLS + j];
#pragma unroll
    for (int j = 0; j < DOM; ++j) hd[j] += ev * dw1[k * DOM + j];
  }
  float d0 = db2[0], d1 = db2[1];
#pragma unroll
  for (int j = 0; j < DOM; ++j) {
    float hv = fmaxf(hd[j], 0.f);
    d0 += hv * dw2[j * 2];
    d1 += hv * dw2[j * 2 + 1];
  }
  if (node < NND) {
#pragma unroll
    for (int j = 0; j < NCLS; ++j) out_cls[(size_t)node * NCLS + j] = c[j];
    out_dom[(size_t)node * 2]     = d0;
    out_dom[(size_t)node * 2 + 1] = d1;
  }
}

// ---------------- host ----------------

extern "C" void kernel_launch(void* const* d_in, const int* in_sizes, int n_in,
                              void* d_out, int out_size, void* d_ws, size_t ws_size,
                              hipStream_t stream) {
  const float* x     = (const float*)d_in[0];
  const int*   ei    = (const int*)d_in[1];
  const float* ppmi  = (const float*)d_in[2];
  const float* W1    = (const float*)d_in[4];
  const float* b1    = (const float*)d_in[5];
  const float* W2    = (const float*)d_in[6];
  const float* b2    = (const float*)d_in[7];
  const float* att_w = (const float*)d_in[8];
  const float* att_b = (const float*)d_in[9];
  const float* cls_w = (const float*)d_in[10];
  const float* cls_b = (const float*)d_in[11];
  const float* dw1   = (const float*)d_in[12];
  const float* db1   = (const float*)d_in[13];
  const float* dw2   = (const float*)d_in[14];
  const float* db2   = (const float*)d_in[15];

  const int* src = ei;
  const int* dst = ei + NED;

  uintptr_t p = (uintptr_t)d_ws;
  auto alloc = [&](size_t bytes) -> void* {
    void* r = (void*)p;
    p += (bytes + 255) & ~(size_t)255;
    return r;
  };
  unsigned int* packed = (unsigned int*)alloc((size_t)NND * 4);
  ushort* rank    = (ushort*)alloc((size_t)NED * 2);
  int*    row_ptr = (int*)   alloc((size_t)(NND + 1) * 4);
  int*    psum    = (int*)   alloc((size_t)NBS * 4);
  float*  dinv_g  = (float*) alloc((size_t)NND * 4);
  float*  dinv_p  = (float*) alloc((size_t)NND * 4);
  int2*   csr     = (int2*)  alloc((size_t)NED * 8);
  ushort* b1hi    = (ushort*)alloc((size_t)FIN * HID * 2);
  ushort* b2hi    = (ushort*)alloc((size_t)HID * ENC * 2);
  ushort* b2lo    = (ushort*)alloc((size_t)HID * ENC * 2);
  ushort* h2b     = (ushort*)alloc((size_t)NND * HID * 2);        // bf16 h2 pair
  ushort* hhs     = (ushort*)alloc((size_t)2 * NND * HID * 2);    // bf16 hg|hp

  float* out_emb = (float*)d_out;
  float* out_cls = (float*)d_out + (size_t)NND * ENC;
  float* out_dom = (float*)d_out + (size_t)NND * (ENC + NCLS);

  // bf16 h_lin lives in the d_out emb region (NND*128*2B == NND*64*4B exactly);
  // dead before agg2 overwrites the region with emb.
  ushort* h_linb = (ushort*)d_out;

  // ---- prep (zero packed + weight conversion, one launch) ----
  k_prep<<<(NND + 255) / 256, 256, 0, stream>>>(W1, b1hi, W2, b2hi, b2lo,
                                                packed);

  // ---- graph preprocessing ----
  k_deg_rank<<<NED / 256, 256, 0, stream>>>(dst, ppmi, packed, rank);
  k_dinv_scan<<<NBS, SCAN_BS, 0, stream>>>(packed, dinv_g, dinv_p, psum);
  k_scan_b<<<1, 512, 0, stream>>>(psum);
  k_scan_c<<<NBS, SCAN_BS, 0, stream>>>(packed, psum, row_ptr);
  k_scatter<<<NED / 256, 256, 0, stream>>>(src, dst, ppmi, row_ptr, rank,
                                           dinv_g, dinv_p, csr);

  // ---- encoder ----
  gemm1_lds<<<(NND + 127) / 128, 256, 0, stream>>>(x, b1hi, h_linb);
  k_agg1<<<(NND * 64) / 256, 256, 0, stream>>>(h_linb, row_ptr, csr,
                                               dinv_g, dinv_p, b1, hhs);
  gemm2_split<4><<<(2 * NND + 255) / 256, 256, 0, stream>>>(
      hhs, b2hi, b2lo, h2b, 2 * NND, HID, ENC);
  k_agg2<<<(NND * 64) / 256, 256, 0, stream>>>(h2b, row_ptr, csr,
                                               dinv_g, dinv_p, b2, att_w, att_b, out_emb);

  // ---- heads ----
  k_head<<<(NND + 127) / 128, 128, 0, stream>>>(out_emb, cls_w, cls_b, dw1, db1,
                                                dw2, db2, out_cls, out_dom);
}

// Round 13
// 422.957 us; speedup vs baseline: 1.2948x; 1.0099x over previous
//
#include <hip/hip_runtime.h>
#include <math.h>
#include <stdint.h>

#define NND  100000   // nodes
#define NED  1600000  // edges (without self loops)
#define FIN  512
#define HID  128
#define ENC  64
#define NCLS 10
#define DOM  40

#define SCAN_BS 256
#define NBS ((NND + SCAN_BS - 1) / SCAN_BS)   // 391

typedef __attribute__((ext_vector_type(8))) short short8v;
typedef __attribute__((ext_vector_type(8))) unsigned short ushort8v;
typedef __attribute__((ext_vector_type(4))) float f32x4;
typedef __attribute__((ext_vector_type(4))) unsigned int uint4v;

// ---------------- helpers ----------------

__device__ inline void split8(const float4 a, const float4 b,
                              short8v& hi, short8v& lo) {
  float f[8] = {a.x, a.y, a.z, a.w, b.x, b.y, b.z, b.w};
  uint4v H, L;
#pragma unroll
  for (int i = 0; i < 4; ++i) {
    unsigned int u0 = __float_as_uint(f[2 * i]);
    unsigned int u1 = __float_as_uint(f[2 * i + 1]);
    H[i] = (u0 >> 16) | (u1 & 0xffff0000u);
    float l0 = f[2 * i]     - __uint_as_float(u0 & 0xffff0000u);
    float l1 = f[2 * i + 1] - __uint_as_float(u1 & 0xffff0000u);
    L[i] = (__float_as_uint(l0) >> 16) | (__float_as_uint(l1) & 0xffff0000u);
  }
  hi = __builtin_bit_cast(short8v, H);
  lo = __builtin_bit_cast(short8v, L);
}

__device__ inline ushort f2bf_rne(float x) {
  unsigned int u = __float_as_uint(x);
  unsigned int r = u + 0x7fffu + ((u >> 16) & 1u);
  return (ushort)(r >> 16);
}

__device__ inline float bf2f(unsigned short v) {
  return __uint_as_float((unsigned int)v << 16);
}

__device__ inline void gload_lds16(const float* gp, float* lp) {
  __builtin_amdgcn_global_load_lds(
      (const __attribute__((address_space(1))) void*)gp,
      (__attribute__((address_space(3))) void*)lp, 16, 0, 0);
}

// ---------------- prep: zero packed + convert W1(RNE) / W2(split) ------------

__global__ void k_prep(const float* __restrict__ W1, ushort* __restrict__ b1hi,
                       const float* __restrict__ W2,
                       ushort* __restrict__ b2hi, ushort* __restrict__ b2lo,
                       unsigned int* __restrict__ packed) {
  int id = blockIdx.x * 256 + threadIdx.x;
  if (id < NND) packed[id] = 0u;
  if (id < FIN * HID) {
    int k = id / HID, c = id % HID;
    size_t o = ((size_t)(k >> 3) * HID + c) * 8 + (k & 7);
    b1hi[o] = f2bf_rne(W1[id]);
  } else {
    int id2 = id - FIN * HID;
    if (id2 >= HID * ENC) return;
    int k = id2 / ENC, c = id2 % ENC;
    float x = W2[id2];
    unsigned int u = __float_as_uint(x);
    ushort h = (ushort)(u >> 16);
    float lo = x - __uint_as_float(u & 0xffff0000u);
    ushort l = (ushort)(__float_as_uint(lo) >> 16);
    size_t o = ((size_t)(k >> 3) * ENC + c) * 8 + (k & 7);
    b2hi[o] = h;
    b2lo[o] = l;
  }
}

// ---------------- degree + rank: ONE packed 32-bit atomic per edge -----------
// packed[d]: bits [25,32) = count (deg <= 127), bits [0,25) = sum(ppmi) 2^-18.

__global__ void k_deg_rank(const int* __restrict__ dst, const float* __restrict__ ppmi,
                           unsigned int* __restrict__ packed,
                           ushort* __restrict__ rank) {
  int e = blockIdx.x * blockDim.x + threadIdx.x;
  if (e >= NED) return;
  int d = dst[e];
  unsigned int fx = (unsigned int)(ppmi[e] * 262144.0f + 0.5f);  // 2^18 scale
  unsigned int v = (1u << 25) | fx;
  unsigned int old = atomicAdd(&packed[d], v);
  rank[e] = (ushort)(old >> 25);
}

// ---------------- dinv + scan_a fused (per-node pass) ------------------------

__global__ void k_dinv_scan(const unsigned int* __restrict__ packed,
                            float* __restrict__ dinv_g, float* __restrict__ dinv_p,
                            int* __restrict__ psum) {
  __shared__ int s[SCAN_BS];
  int t = threadIdx.x, i = blockIdx.x * SCAN_BS + t;
  int cnt = 0;
  if (i < NND) {
    unsigned int pk = packed[i];
    cnt = (int)(pk >> 25);
    float dp = (float)(pk & 0x1FFFFFFu) * (1.0f / 262144.0f);
    dinv_g[i] = 1.0f / sqrtf((float)cnt + 1.0f);
    dinv_p[i] = 1.0f / sqrtf(dp + 1.0f);
  }
  s[t] = cnt;
  __syncthreads();
  for (int o = SCAN_BS / 2; o; o >>= 1) {
    if (t < o) s[t] += s[t + o];
    __syncthreads();
  }
  if (t == 0) psum[blockIdx.x] = s[0];
}

__global__ void k_scan_b(int* __restrict__ psum) {
  __shared__ int s[512];
  int t = threadIdx.x;
  int v = (t < NBS) ? psum[t] : 0;
  s[t] = v;
  __syncthreads();
  for (int o = 1; o < 512; o <<= 1) {
    int add = (t >= o) ? s[t - o] : 0;
    __syncthreads();
    s[t] += add;
    __syncthreads();
  }
  if (t < NBS) psum[t] = s[t] - v;   // exclusive
}

__global__ void k_scan_c(const unsigned int* __restrict__ packed,
                         const int* __restrict__ psum, int* __restrict__ row_ptr) {
  __shared__ int s[SCAN_BS];
  int t = threadIdx.x, i = blockIdx.x * SCAN_BS + t;
  int v = (i < NND) ? (int)(packed[i] >> 25) : 0;
  s[t] = v;
  __syncthreads();
  for (int o = 1; o < SCAN_BS; o <<= 1) {
    int add = (t >= o) ? s[t - o] : 0;
    __syncthreads();
    s[t] += add;
    __syncthreads();
  }
  if (i < NND) row_ptr[i] = psum[blockIdx.x] + s[t] - v;
  if (i == NND - 1) row_ptr[NND] = psum[blockIdx.x] + s[t];
}

// ---------------- CSR scatter: 8B record {src, gn_bf16|pn_bf16<<16} ----------

__global__ void k_scatter(const int* __restrict__ src, const int* __restrict__ dst,
                          const float* __restrict__ ppmi,
                          const int* __restrict__ row_ptr, const ushort* __restrict__ rank,
                          const float* __restrict__ dinv_g, const float* __restrict__ dinv_p,
                          int2* __restrict__ csr) {
  int e = blockIdx.x * blockDim.x + threadIdx.x;
  if (e >= NED) return;
  int s = src[e], d = dst[e];
  int pos = row_ptr[d] + (int)rank[e];
  ushort gn = f2bf_rne(dinv_g[s] * dinv_g[d]);
  ushort pn = f2bf_rne(dinv_p[s] * ppmi[e] * dinv_p[d]);
  int2 rec;
  rec.x = s;
  rec.y = (int)gn | ((int)pn << 16);
  csr[pos] = rec;
}

// ---------------- GEMM1: h_linb(bf16) = x @ W1, LDS-staged 2-term MFMA -------
// 64x128 block tile (was 128x128): grid 1563 blocks -> 2x the waves of R12,
// fixing the grid-limited 24% occupancy. 4 waves = 2x2, wave tile 32x64.
// BK=32; A fp32 -> LDS (2 x [64x32], 16 KB) via global_load_lds w=16,
// double-buffered; 16B-chunk XOR swizzle both-sides (slot c of row r holds
// global chunk c^(r&7)). 2-term split-bf16 (W1 RNE).

__global__ __launch_bounds__(256, 4) void gemm1_lds(
    const float* __restrict__ A, const ushort* __restrict__ Bhi,
    ushort* __restrict__ C) {
  __shared__ float At[2][64 * 32];
  const int tid = threadIdx.x;
  const int lane = tid & 63;
  const int w = tid >> 6;
  const int wr = w >> 1, wc = w & 1;
  const int g = lane >> 4;
  const int l16 = lane & 15;
  const int row_base = blockIdx.x * 64;

  // staging: 2 issues x 16B per thread; tile = 64x32 floats = 2048
  size_t srow[2]; int scol[2];
#pragma unroll
  for (int i = 0; i < 2; ++i) {
    int ee = i * 1024 + tid * 4;
    int r = ee >> 5;
    int chunk_lds = (ee >> 2) & 7;
    int chunk_g = chunk_lds ^ (r & 7);
    int rr = row_base + r; if (rr >= NND) rr = NND - 1;
    srow[i] = (size_t)rr * FIN;
    scol[i] = chunk_g * 4;
  }

  int coln[4];
#pragma unroll
  for (int n = 0; n < 4; ++n) coln[n] = wc * 64 + n * 16 + l16;
  int arow_l[2];
#pragma unroll
  for (int m = 0; m < 2; ++m) arow_l[m] = wr * 32 + m * 16 + l16;

  f32x4 acc[2][4] = {};

#pragma unroll
  for (int i = 0; i < 2; ++i)
    gload_lds16(A + srow[i] + 0 + scol[i], &At[0][i * 1024 + tid * 4]);
  __syncthreads();

  for (int t = 0; t < FIN / 32; ++t) {
    const int cur = t & 1;
    if (t + 1 < FIN / 32) {
      const int k0n = (t + 1) * 32;
#pragma unroll
      for (int i = 0; i < 2; ++i)
        gload_lds16(A + srow[i] + k0n + scol[i], &At[cur ^ 1][i * 1024 + tid * 4]);
    }

    short8v ah[2], al[2];
#pragma unroll
    for (int m = 0; m < 2; ++m) {
      int r = arow_l[m];
      int c0 = (((g * 2)     ^ (r & 7)) << 2);
      int c1 = (((g * 2 + 1) ^ (r & 7)) << 2);
      float4 a0 = *(const float4*)&At[cur][r * 32 + c0];
      float4 a1 = *(const float4*)&At[cur][r * 32 + c1];
      split8(a0, a1, ah[m], al[m]);
    }

    short8v bh[4];
    const int kc = t * 4 + g;
#pragma unroll
    for (int n = 0; n < 4; ++n)
      bh[n] = *(const short8v*)(Bhi + ((size_t)kc * HID + coln[n]) * 8);

#pragma unroll
    for (int m = 0; m < 2; ++m)
#pragma unroll
      for (int n = 0; n < 4; ++n) {
        acc[m][n] = __builtin_amdgcn_mfma_f32_16x16x32_bf16(ah[m], bh[n], acc[m][n], 0, 0, 0);
        acc[m][n] = __builtin_amdgcn_mfma_f32_16x16x32_bf16(al[m], bh[n], acc[m][n], 0, 0, 0);
      }

    __syncthreads();
  }

  // C/D layout: col = lane&15, row = (lane>>4)*4 + reg; wave row base wr*32
#pragma unroll
  for (int m = 0; m < 2; ++m)
#pragma unroll
    for (int i = 0; i < 4; ++i) {
      int r = row_base + wr * 32 + m * 16 + g * 4 + i;
      if (r < NND) {
#pragma unroll
        for (int n = 0; n < 4; ++n)
          C[(size_t)r * HID + coln[n]] = f2bf_rne(acc[m][n][i]);
      }
    }
}

// ---------------- GEMM2: h2b(bf16) = [hg;hp] @ W2, register-A bf16 -----------
// 128-row block tile, wave tile 32x64 (4 waves stacked in M): grid 1563,
// 2x the waves of R12. launch_bounds(256,4): est ~90 VGPR, spill-free.

__global__ __launch_bounds__(256, 4) void gemm2_split(
    const ushort* __restrict__ As, const ushort* __restrict__ Bhi,
    const ushort* __restrict__ Blo, ushort* __restrict__ C,
    int M, int K, int Nc) {
  const int lane = threadIdx.x & 63;
  const int w = threadIdx.x >> 6;
  const int g = lane >> 4;
  const int l16 = lane & 15;
  const int row_base = blockIdx.x * 128 + w * 32;

  size_t arow[2];
#pragma unroll
  for (int m = 0; m < 2; ++m) {
    int r = row_base + m * 16 + l16;
    if (r >= M) r = M - 1;
    arow[m] = (size_t)r * K;
  }
  int coln[4];
#pragma unroll
  for (int n = 0; n < 4; ++n) coln[n] = n * 16 + l16;

  f32x4 acc[2][4] = {};

  for (int k0 = 0; k0 < K; k0 += 32) {
    short8v ah[2];
#pragma unroll
    for (int m = 0; m < 2; ++m)
      ah[m] = *(const short8v*)(As + arow[m] + k0 + g * 8);
    short8v bh[4], bl[4];
    const int kc = (k0 >> 3) + g;
#pragma unroll
    for (int n = 0; n < 4; ++n) {
      size_t off = ((size_t)kc * Nc + coln[n]) * 8;
      bh[n] = *(const short8v*)(Bhi + off);
      bl[n] = *(const short8v*)(Blo + off);
    }
#pragma unroll
    for (int m = 0; m < 2; ++m)
#pragma unroll
      for (int n = 0; n < 4; ++n) {
        acc[m][n] = __builtin_amdgcn_mfma_f32_16x16x32_bf16(ah[m], bh[n], acc[m][n], 0, 0, 0);
        acc[m][n] = __builtin_amdgcn_mfma_f32_16x16x32_bf16(ah[m], bl[n], acc[m][n], 0, 0, 0);
      }
  }

#pragma unroll
  for (int m = 0; m < 2; ++m)
#pragma unroll
    for (int i = 0; i < 4; ++i) {
      int r = row_base + m * 16 + g * 4 + i;
      if (r < M) {
#pragma unroll
        for (int n = 0; n < 4; ++n) {
          int c = coln[n];
          size_t o = (r < NND) ? ((size_t)r * 128 + c)
                               : ((size_t)(r - NND) * 128 + 64 + c);
          C[o] = f2bf_rne(acc[m][n][i]);
        }
      }
    }
}

// ---------------- layer-1 aggregation: bf16 gathers, 4 edges in flight -------

__global__ __launch_bounds__(256) void k_agg1(
    const ushort* __restrict__ hlinb, const int* __restrict__ row_ptr,
    const int2* __restrict__ csr,
    const float* __restrict__ dinv_g, const float* __restrict__ dinv_p,
    const float* __restrict__ b1, ushort* __restrict__ hhs) {
  int wid = (blockIdx.x * blockDim.x + threadIdx.x) >> 6;
  int lane = threadIdx.x & 63;
  if (wid >= NND) return;
  const int gp = lane >> 4;
  const int t  = lane & 15;
  float sg = dinv_g[wid]; sg *= sg;
  float sp = dinv_p[wid]; sp *= sp;

  float ag[8] = {}, ap[8] = {};
  if (gp == 0) {
    ushort8v v = *(const ushort8v*)(hlinb + (size_t)wid * HID + 8 * t);
#pragma unroll
    for (int i = 0; i < 8; ++i) {
      float f = bf2f(v[i]);
      ag[i] = f * sg; ap[i] = f * sp;
    }
  }
  int e0 = row_ptr[wid], e1 = row_ptr[wid + 1];
  int k = e0 + gp;
  if (k < e1) {
    int2 rec = csr[k];
    while (true) {
      int kn = k + 4;
      int2 nrec = csr[kn < e1 ? kn : k];      // clamped prefetch
      float wg = bf2f((ushort)(rec.y & 0xffff));
      float wp = bf2f((ushort)((unsigned)rec.y >> 16));
      ushort8v u = *(const ushort8v*)(hlinb + (size_t)rec.x * HID + 8 * t);
#pragma unroll
      for (int i = 0; i < 8; ++i) {
        float f = bf2f(u[i]);
        ag[i] = fmaf(f, wg, ag[i]);
        ap[i] = fmaf(f, wp, ap[i]);
      }
      if (kn >= e1) break;
      k = kn; rec = nrec;
    }
  }
#pragma unroll
  for (int i = 0; i < 8; ++i) {
    ag[i] += __shfl_xor(ag[i], 32); ap[i] += __shfl_xor(ap[i], 32);
    ag[i] += __shfl_xor(ag[i], 16); ap[i] += __shfl_xor(ap[i], 16);
  }

  float bb[8];
  *(float4*)&bb[0] = *(const float4*)(b1 + 8 * t);
  *(float4*)&bb[4] = *(const float4*)(b1 + 8 * t + 4);
  if (gp == 0 || gp == 2) {
    ushort8v outv;
#pragma unroll
    for (int i = 0; i < 8; ++i) {
      float v = (gp == 0) ? fmaxf(ag[i] + bb[i], 0.f) : fmaxf(ap[i] + bb[i], 0.f);
      outv[i] = f2bf_rne(v);
    }
    size_t row = (gp == 0) ? (size_t)wid : (size_t)(NND + wid);
    *(ushort8v*)(hhs + row * HID + 8 * t) = outv;
  }
}

// ---------------- layer-2 aggregation + attention -> emb ---------------------

__global__ __launch_bounds__(256) void k_agg2(
    const ushort* __restrict__ h2b, const int* __restrict__ row_ptr,
    const int2* __restrict__ csr,
    const float* __restrict__ dinv_g, const float* __restrict__ dinv_p,
    const float* __restrict__ b2, const float* __restrict__ att_w,
    const float* __restrict__ att_b, float* __restrict__ out_emb) {
  int wid = (blockIdx.x * blockDim.x + threadIdx.x) >> 6;
  int lane = threadIdx.x & 63;
  if (wid >= NND) return;
  const int gp = lane >> 4;
  const int t  = lane & 15;
  const int br = t >> 3;            // 0 = g branch, 1 = p branch
  const int f0 = (t & 7) * 8;       // feature base within branch
  float sg = dinv_g[wid]; sg *= sg;
  float sp = dinv_p[wid]; sp *= sp;
  const float sw = br ? sp : sg;

  float acc[8] = {};
  if (gp == 0) {
    ushort8v v = *(const ushort8v*)(h2b + (size_t)wid * 128 + 8 * t);
#pragma unroll
    for (int i = 0; i < 8; ++i) acc[i] = bf2f(v[i]) * sw;
  }
  int e0 = row_ptr[wid], e1 = row_ptr[wid + 1];
  int k = e0 + gp;
  if (k < e1) {
    int2 rec = csr[k];
    while (true) {
      int kn = k + 4;
      int2 nrec = csr[kn < e1 ? kn : k];
      float w = br ? bf2f((ushort)((unsigned)rec.y >> 16))
                   : bf2f((ushort)(rec.y & 0xffff));
      ushort8v u = *(const ushort8v*)(h2b + (size_t)rec.x * 128 + 8 * t);
#pragma unroll
      for (int i = 0; i < 8; ++i) acc[i] = fmaf(bf2f(u[i]), w, acc[i]);
      if (kn >= e1) break;
      k = kn; rec = nrec;
    }
  }
#pragma unroll
  for (int i = 0; i < 8; ++i) {
    acc[i] += __shfl_xor(acc[i], 32);
    acc[i] += __shfl_xor(acc[i], 16);
  }

  float bb[8];
  *(float4*)&bb[0] = *(const float4*)(b2 + f0);
  *(float4*)&bb[4] = *(const float4*)(b2 + f0 + 4);
  float v[8];
#pragma unroll
  for (int i = 0; i < 8; ++i) v[i] = acc[i] + bb[i];

  float aw[8];
  *(float4*)&aw[0] = *(const float4*)(att_w + f0);
  *(float4*)&aw[4] = *(const float4*)(att_w + f0 + 4);
  float part = 0.f;
#pragma unroll
  for (int i = 0; i < 8; ++i) part = fmaf(v[i], aw[i], part);
  part += __shfl_xor(part, 4);
  part += __shfl_xor(part, 2);
  part += __shfl_xor(part, 1);
  float other = __shfl_xor(part, 8);
  float ab = att_b[0];
  float lg = (br ? other : part) + ab;
  float lp = (br ? part : other) + ab;
  float mx = fmaxf(lg, lp);
  float eg = expf(lg - mx), ep2 = expf(lp - mx);
  float wsm = eg / (eg + ep2);          // weight of g branch

  float ov[8];
#pragma unroll
  for (int i = 0; i < 8; ++i) ov[i] = __shfl_xor(v[i], 8);
  if (gp == 0 && br == 0) {
    float4* dst = (float4*)(out_emb + (size_t)wid * 64 + f0);
    float4 o0, o1;
    o0.x = wsm * v[0] + (1.f - wsm) * ov[0];
    o0.y = wsm * v[1] + (1.f - wsm) * ov[1];
    o0.z = wsm * v[2] + (1.f - wsm) * ov[2];
    o0.w = wsm * v[3] + (1.f - wsm) * ov[3];
    o1.x = wsm * v[4] + (1.f - wsm) * ov[4];
    o1.y = wsm * v[5] + (1.f - wsm) * ov[5];
    o1.z = wsm * v[6] + (1.f - wsm) * ov[6];
    o1.w = wsm * v[7] + (1.f - wsm) * ov[7];
    dst[0] = o0;
    dst[1] = o1;
  }
}

// ---------------- class + domain heads --------------

__global__ __launch_bounds__(128) void k_head(
    const float* __restrict__ emb,
    const float* __restrict__ cls_w, const float* __restrict__ cls_b,
    const float* __restrict__ dw1, const float* __restrict__ db1,
    const float* __restrict__ dw2, const float* __restrict__ db2,
    float* __restrict__ out_cls, float* __restrict__ out_dom) {
  __shared__ float se[128 * 65];
  const int t = threadIdx.x;
  const int base = blockIdx.x * 128;
  for (int c = 0; c < 64; ++c) {
    int idx = c * 128 + t;
    int nl = idx >> 6, k = idx & 63;
    size_t g = (size_t)base * ENC + idx;
    float v = (g < (size_t)NND * ENC) ? emb[g] : 0.f;
    se[nl * 65 + k] = v;
  }
  __syncthreads();

  int node = base + t;
  float c[NCLS], hd[DOM];
#pragma unroll
  for (int j = 0; j < NCLS; ++j) c[j] = cls_b[j];
#pragma unroll
  for (int j = 0; j < DOM; ++j) hd[j] = db1[j];

  for (int k = 0; k < ENC; ++k) {
    float ev = se[t * 65 + k];
#pragma unroll
    for (int j = 0; j < NCLS; ++j) c[j] += ev * cls_w[k * NCLS + j];
#pragma unroll
    for (int j = 0; j < DOM; ++j) hd[j] += ev * dw1[k * DOM + j];
  }
  float d0 = db2[0], d1 = db2[1];
#pragma unroll
  for (int j = 0; j < DOM; ++j) {
    float hv = fmaxf(hd[j], 0.f);
    d0 += hv * dw2[j * 2];
    d1 += hv * dw2[j * 2 + 1];
  }
  if (node < NND) {
#pragma unroll
    for (int j = 0; j < NCLS; ++j) out_cls[(size_t)node * NCLS + j] = c[j];
    out_dom[(size_t)node * 2]     = d0;
    out_dom[(size_t)node * 2 + 1] = d1;
  }
}

// ---------------- host ----------------

extern "C" void kernel_launch(void* const* d_in, const int* in_sizes, int n_in,
                              void* d_out, int out_size, void* d_ws, size_t ws_size,
                              hipStream_t stream) {
  const float* x     = (const float*)d_in[0];
  const int*   ei    = (const int*)d_in[1];
  const float* ppmi  = (const float*)d_in[2];
  const float* W1    = (const float*)d_in[4];
  const float* b1    = (const float*)d_in[5];
  const float* W2    = (const float*)d_in[6];
  const float* b2    = (const float*)d_in[7];
  const float* att_w = (const float*)d_in[8];
  const float* att_b = (const float*)d_in[9];
  const float* cls_w = (const float*)d_in[10];
  const float* cls_b = (const float*)d_in[11];
  const float* dw1   = (const float*)d_in[12];
  const float* db1   = (const float*)d_in[13];
  const float* dw2   = (const float*)d_in[14];
  const float* db2   = (const float*)d_in[15];

  const int* src = ei;
  const int* dst = ei + NED;

  uintptr_t p = (uintptr_t)d_ws;
  auto alloc = [&](size_t bytes) -> void* {
    void* r = (void*)p;
    p += (bytes + 255) & ~(size_t)255;
    return r;
  };
  unsigned int* packed = (unsigned int*)alloc((size_t)NND * 4);
  ushort* rank    = (ushort*)alloc((size_t)NED * 2);
  int*    row_ptr = (int*)   alloc((size_t)(NND + 1) * 4);
  int*    psum    = (int*)   alloc((size_t)NBS * 4);
  float*  dinv_g  = (float*) alloc((size_t)NND * 4);
  float*  dinv_p  = (float*) alloc((size_t)NND * 4);
  int2*   csr     = (int2*)  alloc((size_t)NED * 8);
  ushort* b1hi    = (ushort*)alloc((size_t)FIN * HID * 2);
  ushort* b2hi    = (ushort*)alloc((size_t)HID * ENC * 2);
  ushort* b2lo    = (ushort*)alloc((size_t)HID * ENC * 2);
  ushort* h2b     = (ushort*)alloc((size_t)NND * HID * 2);        // bf16 h2 pair
  ushort* hhs     = (ushort*)alloc((size_t)2 * NND * HID * 2);    // bf16 hg|hp

  float* out_emb = (float*)d_out;
  float* out_cls = (float*)d_out + (size_t)NND * ENC;
  float* out_dom = (float*)d_out + (size_t)NND * (ENC + NCLS);

  // bf16 h_lin lives in the d_out emb region (NND*128*2B == NND*64*4B exactly);
  // dead before agg2 overwrites the region with emb.
  ushort* h_linb = (ushort*)d_out;

  // ---- prep (zero packed + weight conversion, one launch) ----
  k_prep<<<(NND + 255) / 256, 256, 0, stream>>>(W1, b1hi, W2, b2hi, b2lo,
                                                packed);

  // ---- graph preprocessing ----
  k_deg_rank<<<NED / 256, 256, 0, stream>>>(dst, ppmi, packed, rank);
  k_dinv_scan<<<NBS, SCAN_BS, 0, stream>>>(packed, dinv_g, dinv_p, psum);
  k_scan_b<<<1, 512, 0, stream>>>(psum);
  k_scan_c<<<NBS, SCAN_BS, 0, stream>>>(packed, psum, row_ptr);
  k_scatter<<<NED / 256, 256, 0, stream>>>(src, dst, ppmi, row_ptr, rank,
                                           dinv_g, dinv_p, csr);

  // ---- encoder ----
  gemm1_lds<<<(NND + 63) / 64, 256, 0, stream>>>(x, b1hi, h_linb);
  k_agg1<<<(NND * 64) / 256, 256, 0, stream>>>(h_linb, row_ptr, csr,
                                               dinv_g, dinv_p, b1, hhs);
  gemm2_split<<<(2 * NND + 127) / 128, 256, 0, stream>>>(
      hhs, b2hi, b2lo, h2b, 2 * NND, HID, ENC);
  k_agg2<<<(NND * 64) / 256, 256, 0, stream>>>(h2b, row_ptr, csr,
                                               dinv_g, dinv_p, b2, att_w, att_b, out_emb);

  // ---- heads ----
  k_head<<<(NND + 127) / 128, 128, 0, stream>>>(out_emb, cls_w, cls_b, dw1, db1,
                                                dw2, db2, out_cls, out_dom);
}

// Round 14
// 379.235 us; speedup vs baseline: 1.4440x; 1.1153x over previous
//
#include <hip/hip_runtime.h>
#include <math.h>
#include <stdint.h>

#define NND  100000   // nodes
#define NED  1600000  // edges (without self loops)
#define FIN  512
#define HID  128
#define ENC  64
#define NCLS 10
#define DOM  40

#define SCAN_BS 256
#define NBS ((NND + SCAN_BS - 1) / SCAN_BS)   // 391

// fused phase-1: 1563 gemm blocks (64-row tiles) + 521 deg blocks, 1-per-4
#define NGEMM 1563
#define NDEG  521
#define NPH1  (NGEMM + NDEG)                  // 2084 = 4*521

typedef __attribute__((ext_vector_type(8))) short short8v;
typedef __attribute__((ext_vector_type(8))) unsigned short ushort8v;
typedef __attribute__((ext_vector_type(4))) float f32x4;
typedef __attribute__((ext_vector_type(4))) unsigned int uint4v;

// ---------------- helpers ----------------

__device__ inline void split8(const float4 a, const float4 b,
                              short8v& hi, short8v& lo) {
  float f[8] = {a.x, a.y, a.z, a.w, b.x, b.y, b.z, b.w};
  uint4v H, L;
#pragma unroll
  for (int i = 0; i < 4; ++i) {
    unsigned int u0 = __float_as_uint(f[2 * i]);
    unsigned int u1 = __float_as_uint(f[2 * i + 1]);
    H[i] = (u0 >> 16) | (u1 & 0xffff0000u);
    float l0 = f[2 * i]     - __uint_as_float(u0 & 0xffff0000u);
    float l1 = f[2 * i + 1] - __uint_as_float(u1 & 0xffff0000u);
    L[i] = (__float_as_uint(l0) >> 16) | (__float_as_uint(l1) & 0xffff0000u);
  }
  hi = __builtin_bit_cast(short8v, H);
  lo = __builtin_bit_cast(short8v, L);
}

__device__ inline ushort f2bf_rne(float x) {
  unsigned int u = __float_as_uint(x);
  unsigned int r = u + 0x7fffu + ((u >> 16) & 1u);
  return (ushort)(r >> 16);
}

__device__ inline float bf2f(unsigned short v) {
  return __uint_as_float((unsigned int)v << 16);
}

__device__ inline void gload_lds16(const float* gp, float* lp) {
  __builtin_amdgcn_global_load_lds(
      (const __attribute__((address_space(1))) void*)gp,
      (__attribute__((address_space(3))) void*)lp, 16, 0, 0);
}

// ---------------- prep: zero packed + convert W1(RNE) / W2(split) ------------

__global__ void k_prep(const float* __restrict__ W1, ushort* __restrict__ b1hi,
                       const float* __restrict__ W2,
                       ushort* __restrict__ b2hi, ushort* __restrict__ b2lo,
                       unsigned int* __restrict__ packed) {
  int id = blockIdx.x * 256 + threadIdx.x;
  if (id < NND) packed[id] = 0u;
  if (id < FIN * HID) {
    int k = id / HID, c = id % HID;
    size_t o = ((size_t)(k >> 3) * HID + c) * 8 + (k & 7);
    b1hi[o] = f2bf_rne(W1[id]);
  } else {
    int id2 = id - FIN * HID;
    if (id2 >= HID * ENC) return;
    int k = id2 / ENC, c = id2 % ENC;
    float x = W2[id2];
    unsigned int u = __float_as_uint(x);
    ushort h = (ushort)(u >> 16);
    float lo = x - __uint_as_float(u & 0xffff0000u);
    ushort l = (ushort)(__float_as_uint(lo) >> 16);
    size_t o = ((size_t)(k >> 3) * ENC + c) * 8 + (k & 7);
    b2hi[o] = h;
    b2lo[o] = l;
  }
}

// ---------------- fused phase 1: gemm1 blocks + deg/rank blocks --------------
// deg blocks (bi%4==0, 521 of them, resident from the first dispatch wave):
//   grid-stride over edges; packed[d] += (1<<25)|fix18(ppmi); rank = old>>25.
//   ~12 independent atomics/thread; 133k threads -> near device atomic cap.
// gemm blocks: h_linb(bf16) = x @ W1. 64x128 tile, BK=32, 4 waves (2x2),
//   wave tile 32x64; A fp32 -> LDS (2 x 8 KB) via global_load_lds w=16,
//   double-buffered, 16B-chunk XOR swizzle both-sides; 2-term split-bf16.

__global__ __launch_bounds__(256, 4) void k_phase1(
    const float* __restrict__ A, const ushort* __restrict__ Bhi,
    ushort* __restrict__ C,
    const int* __restrict__ dst, const float* __restrict__ ppmi,
    unsigned int* __restrict__ packed, ushort* __restrict__ rank) {
  __shared__ float At[2][64 * 32];
  const int bi = blockIdx.x;
  const int tid = threadIdx.x;

  if ((bi & 3) == 0) {
    // ---- degree/rank path ----
    for (int e = (bi >> 2) * 256 + tid; e < NED; e += NDEG * 256) {
      int d = dst[e];
      unsigned int fx = (unsigned int)(ppmi[e] * 262144.0f + 0.5f);
      unsigned int v = (1u << 25) | fx;
      unsigned int old = atomicAdd(&packed[d], v);
      rank[e] = (ushort)(old >> 25);
    }
    return;
  }

  const int gb = bi - (bi >> 2) - 1;          // 0..1562
  const int lane = tid & 63;
  const int w = tid >> 6;
  const int wr = w >> 1, wc = w & 1;
  const int g = lane >> 4;
  const int l16 = lane & 15;
  const int row_base = gb * 64;

  size_t srow[2]; int scol[2];
#pragma unroll
  for (int i = 0; i < 2; ++i) {
    int ee = i * 1024 + tid * 4;
    int r = ee >> 5;
    int chunk_lds = (ee >> 2) & 7;
    int chunk_g = chunk_lds ^ (r & 7);
    int rr = row_base + r; if (rr >= NND) rr = NND - 1;
    srow[i] = (size_t)rr * FIN;
    scol[i] = chunk_g * 4;
  }

  int coln[4];
#pragma unroll
  for (int n = 0; n < 4; ++n) coln[n] = wc * 64 + n * 16 + l16;
  int arow_l[2];
#pragma unroll
  for (int m = 0; m < 2; ++m) arow_l[m] = wr * 32 + m * 16 + l16;

  f32x4 acc[2][4] = {};

#pragma unroll
  for (int i = 0; i < 2; ++i)
    gload_lds16(A + srow[i] + 0 + scol[i], &At[0][i * 1024 + tid * 4]);
  __syncthreads();

  for (int t = 0; t < FIN / 32; ++t) {
    const int cur = t & 1;
    if (t + 1 < FIN / 32) {
      const int k0n = (t + 1) * 32;
#pragma unroll
      for (int i = 0; i < 2; ++i)
        gload_lds16(A + srow[i] + k0n + scol[i], &At[cur ^ 1][i * 1024 + tid * 4]);
    }

    short8v ah[2], al[2];
#pragma unroll
    for (int m = 0; m < 2; ++m) {
      int r = arow_l[m];
      int c0 = (((g * 2)     ^ (r & 7)) << 2);
      int c1 = (((g * 2 + 1) ^ (r & 7)) << 2);
      float4 a0 = *(const float4*)&At[cur][r * 32 + c0];
      float4 a1 = *(const float4*)&At[cur][r * 32 + c1];
      split8(a0, a1, ah[m], al[m]);
    }

    short8v bh[4];
    const int kc = t * 4 + g;
#pragma unroll
    for (int n = 0; n < 4; ++n)
      bh[n] = *(const short8v*)(Bhi + ((size_t)kc * HID + coln[n]) * 8);

#pragma unroll
    for (int m = 0; m < 2; ++m)
#pragma unroll
      for (int n = 0; n < 4; ++n) {
        acc[m][n] = __builtin_amdgcn_mfma_f32_16x16x32_bf16(ah[m], bh[n], acc[m][n], 0, 0, 0);
        acc[m][n] = __builtin_amdgcn_mfma_f32_16x16x32_bf16(al[m], bh[n], acc[m][n], 0, 0, 0);
      }

    __syncthreads();
  }

  // C/D layout: col = lane&15, row = (lane>>4)*4 + reg; wave row base wr*32
#pragma unroll
  for (int m = 0; m < 2; ++m)
#pragma unroll
    for (int i = 0; i < 4; ++i) {
      int r = row_base + wr * 32 + m * 16 + g * 4 + i;
      if (r < NND) {
#pragma unroll
        for (int n = 0; n < 4; ++n)
          C[(size_t)r * HID + coln[n]] = f2bf_rne(acc[m][n][i]);
      }
    }
}

// ---------------- dinv + scan_a fused (per-node pass) ------------------------

__global__ void k_dinv_scan(const unsigned int* __restrict__ packed,
                            float* __restrict__ dinv_g, float* __restrict__ dinv_p,
                            int* __restrict__ psum) {
  __shared__ int s[SCAN_BS];
  int t = threadIdx.x, i = blockIdx.x * SCAN_BS + t;
  int cnt = 0;
  if (i < NND) {
    unsigned int pk = packed[i];
    cnt = (int)(pk >> 25);
    float dp = (float)(pk & 0x1FFFFFFu) * (1.0f / 262144.0f);
    dinv_g[i] = 1.0f / sqrtf((float)cnt + 1.0f);
    dinv_p[i] = 1.0f / sqrtf(dp + 1.0f);
  }
  s[t] = cnt;
  __syncthreads();
  for (int o = SCAN_BS / 2; o; o >>= 1) {
    if (t < o) s[t] += s[t + o];
    __syncthreads();
  }
  if (t == 0) psum[blockIdx.x] = s[0];
}

__global__ void k_scan_b(int* __restrict__ psum) {
  __shared__ int s[512];
  int t = threadIdx.x;
  int v = (t < NBS) ? psum[t] : 0;
  s[t] = v;
  __syncthreads();
  for (int o = 1; o < 512; o <<= 1) {
    int add = (t >= o) ? s[t - o] : 0;
    __syncthreads();
    s[t] += add;
    __syncthreads();
  }
  if (t < NBS) psum[t] = s[t] - v;   // exclusive
}

__global__ void k_scan_c(const unsigned int* __restrict__ packed,
                         const int* __restrict__ psum, int* __restrict__ row_ptr) {
  __shared__ int s[SCAN_BS];
  int t = threadIdx.x, i = blockIdx.x * SCAN_BS + t;
  int v = (i < NND) ? (int)(packed[i] >> 25) : 0;
  s[t] = v;
  __syncthreads();
  for (int o = 1; o < SCAN_BS; o <<= 1) {
    int add = (t >= o) ? s[t - o] : 0;
    __syncthreads();
    s[t] += add;
    __syncthreads();
  }
  if (i < NND) row_ptr[i] = psum[blockIdx.x] + s[t] - v;
  if (i == NND - 1) row_ptr[NND] = psum[blockIdx.x] + s[t];
}

// ---------------- CSR scatter: 8B record {src, gn_bf16|pn_bf16<<16} ----------

__global__ void k_scatter(const int* __restrict__ src, const int* __restrict__ dst,
                          const float* __restrict__ ppmi,
                          const int* __restrict__ row_ptr, const ushort* __restrict__ rank,
                          const float* __restrict__ dinv_g, const float* __restrict__ dinv_p,
                          int2* __restrict__ csr) {
  int e = blockIdx.x * blockDim.x + threadIdx.x;
  if (e >= NED) return;
  int s = src[e], d = dst[e];
  int pos = row_ptr[d] + (int)rank[e];
  ushort gn = f2bf_rne(dinv_g[s] * dinv_g[d]);
  ushort pn = f2bf_rne(dinv_p[s] * ppmi[e] * dinv_p[d]);
  int2 rec;
  rec.x = s;
  rec.y = (int)gn | ((int)pn << 16);
  csr[pos] = rec;
}

// ---------------- GEMM2: h2b(bf16) = [hg;hp] @ W2, register-A bf16 -----------
// 128-row block tile, wave tile 32x64 (4 waves stacked in M).

__global__ __launch_bounds__(256, 4) void gemm2_split(
    const ushort* __restrict__ As, const ushort* __restrict__ Bhi,
    const ushort* __restrict__ Blo, ushort* __restrict__ C,
    int M, int K, int Nc) {
  const int lane = threadIdx.x & 63;
  const int w = threadIdx.x >> 6;
  const int g = lane >> 4;
  const int l16 = lane & 15;
  const int row_base = blockIdx.x * 128 + w * 32;

  size_t arow[2];
#pragma unroll
  for (int m = 0; m < 2; ++m) {
    int r = row_base + m * 16 + l16;
    if (r >= M) r = M - 1;
    arow[m] = (size_t)r * K;
  }
  int coln[4];
#pragma unroll
  for (int n = 0; n < 4; ++n) coln[n] = n * 16 + l16;

  f32x4 acc[2][4] = {};

  for (int k0 = 0; k0 < K; k0 += 32) {
    short8v ah[2];
#pragma unroll
    for (int m = 0; m < 2; ++m)
      ah[m] = *(const short8v*)(As + arow[m] + k0 + g * 8);
    short8v bh[4], bl[4];
    const int kc = (k0 >> 3) + g;
#pragma unroll
    for (int n = 0; n < 4; ++n) {
      size_t off = ((size_t)kc * Nc + coln[n]) * 8;
      bh[n] = *(const short8v*)(Bhi + off);
      bl[n] = *(const short8v*)(Blo + off);
    }
#pragma unroll
    for (int m = 0; m < 2; ++m)
#pragma unroll
      for (int n = 0; n < 4; ++n) {
        acc[m][n] = __builtin_amdgcn_mfma_f32_16x16x32_bf16(ah[m], bh[n], acc[m][n], 0, 0, 0);
        acc[m][n] = __builtin_amdgcn_mfma_f32_16x16x32_bf16(ah[m], bl[n], acc[m][n], 0, 0, 0);
      }
  }

#pragma unroll
  for (int m = 0; m < 2; ++m)
#pragma unroll
    for (int i = 0; i < 4; ++i) {
      int r = row_base + m * 16 + g * 4 + i;
      if (r < M) {
#pragma unroll
        for (int n = 0; n < 4; ++n) {
          int c = coln[n];
          size_t o = (r < NND) ? ((size_t)r * 128 + c)
                               : ((size_t)(r - NND) * 128 + 64 + c);
          C[o] = f2bf_rne(acc[m][n][i]);
        }
      }
    }
}

// ---------------- layer-1 aggregation: bf16 gathers, 4 edges in flight -------

__global__ __launch_bounds__(256) void k_agg1(
    const ushort* __restrict__ hlinb, const int* __restrict__ row_ptr,
    const int2* __restrict__ csr,
    const float* __restrict__ dinv_g, const float* __restrict__ dinv_p,
    const float* __restrict__ b1, ushort* __restrict__ hhs) {
  int wid = (blockIdx.x * blockDim.x + threadIdx.x) >> 6;
  int lane = threadIdx.x & 63;
  if (wid >= NND) return;
  const int gp = lane >> 4;
  const int t  = lane & 15;
  float sg = dinv_g[wid]; sg *= sg;
  float sp = dinv_p[wid]; sp *= sp;

  float ag[8] = {}, ap[8] = {};
  if (gp == 0) {
    ushort8v v = *(const ushort8v*)(hlinb + (size_t)wid * HID + 8 * t);
#pragma unroll
    for (int i = 0; i < 8; ++i) {
      float f = bf2f(v[i]);
      ag[i] = f * sg; ap[i] = f * sp;
    }
  }
  int e0 = row_ptr[wid], e1 = row_ptr[wid + 1];
  int k = e0 + gp;
  if (k < e1) {
    int2 rec = csr[k];
    while (true) {
      int kn = k + 4;
      int2 nrec = csr[kn < e1 ? kn : k];      // clamped prefetch
      float wg = bf2f((ushort)(rec.y & 0xffff));
      float wp = bf2f((ushort)((unsigned)rec.y >> 16));
      ushort8v u = *(const ushort8v*)(hlinb + (size_t)rec.x * HID + 8 * t);
#pragma unroll
      for (int i = 0; i < 8; ++i) {
        float f = bf2f(u[i]);
        ag[i] = fmaf(f, wg, ag[i]);
        ap[i] = fmaf(f, wp, ap[i]);
      }
      if (kn >= e1) break;
      k = kn; rec = nrec;
    }
  }
#pragma unroll
  for (int i = 0; i < 8; ++i) {
    ag[i] += __shfl_xor(ag[i], 32); ap[i] += __shfl_xor(ap[i], 32);
    ag[i] += __shfl_xor(ag[i], 16); ap[i] += __shfl_xor(ap[i], 16);
  }

  float bb[8];
  *(float4*)&bb[0] = *(const float4*)(b1 + 8 * t);
  *(float4*)&bb[4] = *(const float4*)(b1 + 8 * t + 4);
  if (gp == 0 || gp == 2) {
    ushort8v outv;
#pragma unroll
    for (int i = 0; i < 8; ++i) {
      float v = (gp == 0) ? fmaxf(ag[i] + bb[i], 0.f) : fmaxf(ap[i] + bb[i], 0.f);
      outv[i] = f2bf_rne(v);
    }
    size_t row = (gp == 0) ? (size_t)wid : (size_t)(NND + wid);
    *(ushort8v*)(hhs + row * HID + 8 * t) = outv;
  }
}

// ---------------- layer-2 aggregation + attention -> emb ---------------------

__global__ __launch_bounds__(256) void k_agg2(
    const ushort* __restrict__ h2b, const int* __restrict__ row_ptr,
    const int2* __restrict__ csr,
    const float* __restrict__ dinv_g, const float* __restrict__ dinv_p,
    const float* __restrict__ b2, const float* __restrict__ att_w,
    const float* __restrict__ att_b, float* __restrict__ out_emb) {
  int wid = (blockIdx.x * blockDim.x + threadIdx.x) >> 6;
  int lane = threadIdx.x & 63;
  if (wid >= NND) return;
  const int gp = lane >> 4;
  const int t  = lane & 15;
  const int br = t >> 3;            // 0 = g branch, 1 = p branch
  const int f0 = (t & 7) * 8;       // feature base within branch
  float sg = dinv_g[wid]; sg *= sg;
  float sp = dinv_p[wid]; sp *= sp;
  const float sw = br ? sp : sg;

  float acc[8] = {};
  if (gp == 0) {
    ushort8v v = *(const ushort8v*)(h2b + (size_t)wid * 128 + 8 * t);
#pragma unroll
    for (int i = 0; i < 8; ++i) acc[i] = bf2f(v[i]) * sw;
  }
  int e0 = row_ptr[wid], e1 = row_ptr[wid + 1];
  int k = e0 + gp;
  if (k < e1) {
    int2 rec = csr[k];
    while (true) {
      int kn = k + 4;
      int2 nrec = csr[kn < e1 ? kn : k];
      float w = br ? bf2f((ushort)((unsigned)rec.y >> 16))
                   : bf2f((ushort)(rec.y & 0xffff));
      ushort8v u = *(const ushort8v*)(h2b + (size_t)rec.x * 128 + 8 * t);
#pragma unroll
      for (int i = 0; i < 8; ++i) acc[i] = fmaf(bf2f(u[i]), w, acc[i]);
      if (kn >= e1) break;
      k = kn; rec = nrec;
    }
  }
#pragma unroll
  for (int i = 0; i < 8; ++i) {
    acc[i] += __shfl_xor(acc[i], 32);
    acc[i] += __shfl_xor(acc[i], 16);
  }

  float bb[8];
  *(float4*)&bb[0] = *(const float4*)(b2 + f0);
  *(float4*)&bb[4] = *(const float4*)(b2 + f0 + 4);
  float v[8];
#pragma unroll
  for (int i = 0; i < 8; ++i) v[i] = acc[i] + bb[i];

  float aw[8];
  *(float4*)&aw[0] = *(const float4*)(att_w + f0);
  *(float4*)&aw[4] = *(const float4*)(att_w + f0 + 4);
  float part = 0.f;
#pragma unroll
  for (int i = 0; i < 8; ++i) part = fmaf(v[i], aw[i], part);
  part += __shfl_xor(part, 4);
  part += __shfl_xor(part, 2);
  part += __shfl_xor(part, 1);
  float other = __shfl_xor(part, 8);
  float ab = att_b[0];
  float lg = (br ? other : part) + ab;
  float lp = (br ? part : other) + ab;
  float mx = fmaxf(lg, lp);
  float eg = expf(lg - mx), ep2 = expf(lp - mx);
  float wsm = eg / (eg + ep2);          // weight of g branch

  float ov[8];
#pragma unroll
  for (int i = 0; i < 8; ++i) ov[i] = __shfl_xor(v[i], 8);
  if (gp == 0 && br == 0) {
    float4* dst = (float4*)(out_emb + (size_t)wid * 64 + f0);
    float4 o0, o1;
    o0.x = wsm * v[0] + (1.f - wsm) * ov[0];
    o0.y = wsm * v[1] + (1.f - wsm) * ov[1];
    o0.z = wsm * v[2] + (1.f - wsm) * ov[2];
    o0.w = wsm * v[3] + (1.f - wsm) * ov[3];
    o1.x = wsm * v[4] + (1.f - wsm) * ov[4];
    o1.y = wsm * v[5] + (1.f - wsm) * ov[5];
    o1.z = wsm * v[6] + (1.f - wsm) * ov[6];
    o1.w = wsm * v[7] + (1.f - wsm) * ov[7];
    dst[0] = o0;
    dst[1] = o1;
  }
}

// ---------------- class + domain heads --------------

__global__ __launch_bounds__(128) void k_head(
    const float* __restrict__ emb,
    const float* __restrict__ cls_w, const float* __restrict__ cls_b,
    const float* __restrict__ dw1, const float* __restrict__ db1,
    const float* __restrict__ dw2, const float* __restrict__ db2,
    float* __restrict__ out_cls, float* __restrict__ out_dom) {
  __shared__ float se[128 * 65];
  const int t = threadIdx.x;
  const int base = blockIdx.x * 128;
  for (int c = 0; c < 64; ++c) {
    int idx = c * 128 + t;
    int nl = idx >> 6, k = idx & 63;
    size_t g = (size_t)base * ENC + idx;
    float v = (g < (size_t)NND * ENC) ? emb[g] : 0.f;
    se[nl * 65 + k] = v;
  }
  __syncthreads();

  int node = base + t;
  float c[NCLS], hd[DOM];
#pragma unroll
  for (int j = 0; j < NCLS; ++j) c[j] = cls_b[j];
#pragma unroll
  for (int j = 0; j < DOM; ++j) hd[j] = db1[j];

  for (int k = 0; k < ENC; ++k) {
    float ev = se[t * 65 + k];
#pragma unroll
    for (int j = 0; j < NCLS; ++j) c[j] += ev * cls_w[k * NCLS + j];
#pragma unroll
    for (int j = 0; j < DOM; ++j) hd[j] += ev * dw1[k * DOM + j];
  }
  float d0 = db2[0], d1 = db2[1];
#pragma unroll
  for (int j = 0; j < DOM; ++j) {
    float hv = fmaxf(hd[j], 0.f);
    d0 += hv * dw2[j * 2];
    d1 += hv * dw2[j * 2 + 1];
  }
  if (node < NND) {
#pragma unroll
    for (int j = 0; j < NCLS; ++j) out_cls[(size_t)node * NCLS + j] = c[j];
    out_dom[(size_t)node * 2]     = d0;
    out_dom[(size_t)node * 2 + 1] = d1;
  }
}

// ---------------- host ----------------

extern "C" void kernel_launch(void* const* d_in, const int* in_sizes, int n_in,
                              void* d_out, int out_size, void* d_ws, size_t ws_size,
                              hipStream_t stream) {
  const float* x     = (const float*)d_in[0];
  const int*   ei    = (const int*)d_in[1];
  const float* ppmi  = (const float*)d_in[2];
  const float* W1    = (const float*)d_in[4];
  const float* b1    = (const float*)d_in[5];
  const float* W2    = (const float*)d_in[6];
  const float* b2    = (const float*)d_in[7];
  const float* att_w = (const float*)d_in[8];
  const float* att_b = (const float*)d_in[9];
  const float* cls_w = (const float*)d_in[10];
  const float* cls_b = (const float*)d_in[11];
  const float* dw1   = (const float*)d_in[12];
  const float* db1   = (const float*)d_in[13];
  const float* dw2   = (const float*)d_in[14];
  const float* db2   = (const float*)d_in[15];

  const int* src = ei;
  const int* dst = ei + NED;

  uintptr_t p = (uintptr_t)d_ws;
  auto alloc = [&](size_t bytes) -> void* {
    void* r = (void*)p;
    p += (bytes + 255) & ~(size_t)255;
    return r;
  };
  unsigned int* packed = (unsigned int*)alloc((size_t)NND * 4);
  ushort* rank    = (ushort*)alloc((size_t)NED * 2);
  int*    row_ptr = (int*)   alloc((size_t)(NND + 1) * 4);
  int*    psum    = (int*)   alloc((size_t)NBS * 4);
  float*  dinv_g  = (float*) alloc((size_t)NND * 4);
  float*  dinv_p  = (float*) alloc((size_t)NND * 4);
  int2*   csr     = (int2*)  alloc((size_t)NED * 8);
  ushort* b1hi    = (ushort*)alloc((size_t)FIN * HID * 2);
  ushort* b2hi    = (ushort*)alloc((size_t)HID * ENC * 2);
  ushort* b2lo    = (ushort*)alloc((size_t)HID * ENC * 2);
  ushort* h2b     = (ushort*)alloc((size_t)NND * HID * 2);        // bf16 h2 pair
  ushort* hhs     = (ushort*)alloc((size_t)2 * NND * HID * 2);    // bf16 hg|hp

  float* out_emb = (float*)d_out;
  float* out_cls = (float*)d_out + (size_t)NND * ENC;
  float* out_dom = (float*)d_out + (size_t)NND * (ENC + NCLS);

  // bf16 h_lin lives in the d_out emb region (NND*128*2B == NND*64*4B exactly);
  // dead before agg2 overwrites the region with emb.
  ushort* h_linb = (ushort*)d_out;

  // ---- prep (zero packed + weight conversion, one launch) ----
  k_prep<<<(NND + 255) / 256, 256, 0, stream>>>(W1, b1hi, W2, b2hi, b2lo,
                                                packed);

  // ---- fused phase 1: gemm1 (x @ W1 -> h_linb) || deg_rank ----
  k_phase1<<<NPH1, 256, 0, stream>>>(x, b1hi, h_linb, dst, ppmi, packed, rank);

  // ---- rest of graph preprocessing ----
  k_dinv_scan<<<NBS, SCAN_BS, 0, stream>>>(packed, dinv_g, dinv_p, psum);
  k_scan_b<<<1, 512, 0, stream>>>(psum);
  k_scan_c<<<NBS, SCAN_BS, 0, stream>>>(packed, psum, row_ptr);
  k_scatter<<<NED / 256, 256, 0, stream>>>(src, dst, ppmi, row_ptr, rank,
                                           dinv_g, dinv_p, csr);

  // ---- encoder ----
  k_agg1<<<(NND * 64) / 256, 256, 0, stream>>>(h_linb, row_ptr, csr,
                                               dinv_g, dinv_p, b1, hhs);
  gemm2_split<<<(2 * NND + 127) / 128, 256, 0, stream>>>(
      hhs, b2hi, b2lo, h2b, 2 * NND, HID, ENC);
  k_agg2<<<(NND * 64) / 256, 256, 0, stream>>>(h2b, row_ptr, csr,
                                               dinv_g, dinv_p, b2, att_w, att_b, out_emb);

  // ---- heads ----
  k_head<<<(NND + 127) / 128, 128, 0, stream>>>(out_emb, cls_w, cls_b, dw1, db1,
                                                dw2, db2, out_cls, out_dom);
}